// Round 16
// baseline (786.225 us; speedup 1.0000x reference)
//
#include <hip/hip_runtime.h>
#include <hip/hip_bf16.h>
#include <math.h>

#define BN_EPS 1e-5f
#define B1 256      // edge-chunk blocks for count/scatter passes (must == blockDim)
#define MAXNB 1024  // max coarse buckets (128 rows each); 100k nodes -> 782

typedef float f32x4 __attribute__((ext_vector_type(4)));
typedef float f32x2 __attribute__((ext_vector_type(2)));
typedef short bf16x8 __attribute__((ext_vector_type(8)));
typedef unsigned short u16x4 __attribute__((ext_vector_type(4)));

__device__ inline unsigned short f2bf(float v) {
    unsigned b = __float_as_uint(v);
    unsigned r = (b + 0x7FFFu + ((b >> 16) & 1u)) >> 16;
    return (unsigned short)r;
}
__device__ inline float bf2f(unsigned short h) {
    return __uint_as_float(((unsigned)h) << 16);
}

// ================= CSR build (atomic-free at global scope) =================
__global__ __launch_bounds__(256) void count_kernel(const int* __restrict__ row,
                                                    int* __restrict__ blockCounts,
                                                    int nB2, int nE, int chunk) {
    __shared__ int hist[MAXNB];
    int t = threadIdx.x;
    for (int b = t; b < nB2; b += 256) hist[b] = 0;
    __syncthreads();
    int s0 = blockIdx.x * chunk;
    int s1 = s0 + chunk;
    if (s1 > nE) s1 = nE;
    for (int j = s0 + t; j < s1; j += 256) atomicAdd(&hist[row[j] >> 7], 1);
    __syncthreads();
    for (int b = t; b < nB2; b += 256) blockCounts[blockIdx.x * nB2 + b] = hist[b];
}

__global__ __launch_bounds__(256) void scan_buckets_kernel(int* __restrict__ blockCounts,
                                                           int* __restrict__ bucketTotal,
                                                           int nB2) {
    int b = blockIdx.x;
    int t = threadIdx.x;
    int lane = t & 63;
    int s = blockCounts[t * nB2 + b];
    int v = s;
#pragma unroll
    for (int d = 1; d < 64; d <<= 1) {
        int u = __shfl_up(v, d);
        if (lane >= d) v += u;
    }
    __shared__ int ws[4];
    if (lane == 63) ws[t >> 6] = v;
    __syncthreads();
    int add = 0;
    for (int i = 0; i < (t >> 6); ++i) add += ws[i];
    v += add;
    blockCounts[t * nB2 + b] = v - s;  // exclusive within bucket
    if (t == 255) bucketTotal[b] = v;
}

__global__ __launch_bounds__(256) void scan_total_kernel(const int* __restrict__ bucketTotal,
                                                         int* __restrict__ bucketBase,
                                                         int* __restrict__ offsets,
                                                         int nB2, int nodes) {
    int t = threadIdx.x;
    int lane = t & 63;
    int b0 = t * 4;
    int c0 = (b0 + 0 < nB2) ? bucketTotal[b0 + 0] : 0;
    int c1 = (b0 + 1 < nB2) ? bucketTotal[b0 + 1] : 0;
    int c2 = (b0 + 2 < nB2) ? bucketTotal[b0 + 2] : 0;
    int c3 = (b0 + 3 < nB2) ? bucketTotal[b0 + 3] : 0;
    int s = c0 + c1 + c2 + c3;
    int v = s;
#pragma unroll
    for (int d = 1; d < 64; d <<= 1) {
        int u = __shfl_up(v, d);
        if (lane >= d) v += u;
    }
    __shared__ int ws[4];
    if (lane == 63) ws[t >> 6] = v;
    __syncthreads();
    int add = 0;
    for (int i = 0; i < (t >> 6); ++i) add += ws[i];
    v += add;
    int p = v - s;
    if (b0 + 0 <= nB2) bucketBase[b0 + 0] = p; p += c0;
    if (b0 + 1 <= nB2) bucketBase[b0 + 1] = p; p += c1;
    if (b0 + 2 <= nB2) bucketBase[b0 + 2] = p; p += c2;
    if (b0 + 3 <= nB2) bucketBase[b0 + 3] = p;
    if (t == 255) offsets[nodes] = v;  // grand total == nE
}

__global__ __launch_bounds__(256) void scatter2_kernel(const int* __restrict__ row,
                                                       const int* __restrict__ col,
                                                       const float* __restrict__ val,
                                                       const int* __restrict__ blockCounts,
                                                       const int* __restrict__ bucketBase,
                                                       int2* __restrict__ tmp,
                                                       int nB2, int nE, int chunk) {
    __shared__ int cur[MAXNB];
    int t = threadIdx.x;
    for (int b = t; b < nB2; b += 256)
        cur[b] = bucketBase[b] + blockCounts[blockIdx.x * nB2 + b];
    __syncthreads();
    int s0 = blockIdx.x * chunk;
    int s1 = s0 + chunk;
    if (s1 > nE) s1 = nE;
    for (int j = s0 + t; j < s1; j += 256) {
        int r = row[j];
        int p = atomicAdd(&cur[r >> 7], 1);  // LDS atomic
        int2 e;
        e.x = col[j] | ((r & 127) << 20);
        e.y = __float_as_int(val[j]);
        tmp[p] = e;
    }
}

// Pass 3: one block per 128-row bucket. Counting sort into (localrow, col>>12)
// bins -> each row's edges contiguous AND column-block-ordered. Concurrent
// waves then sweep aligned column bands -> gather working set becomes
// L2-resident. Also emits per-row CSR offsets from the bin boundaries.
__global__ __launch_bounds__(256) void bucket_sort2_kernel(const int* __restrict__ bucketBase,
                                                           const int2* __restrict__ tmp,
                                                           int2* __restrict__ edges,
                                                           int* __restrict__ offsets,
                                                           int nodes) {
    __shared__ int bcnt[4096];  // 128 rows x 32 col-blocks (col>>12, col<2^20)
    __shared__ int bcur[4096];
    __shared__ int wsum[4];
    int b = blockIdx.x;
    int t = threadIdx.x;
    int base = bucketBase[b];
    int cntE = bucketBase[b + 1] - base;
    for (int i = t; i < 4096; i += 256) bcnt[i] = 0;
    __syncthreads();
    for (int j = t; j < cntE; j += 256) {
        int ex = tmp[base + j].x;
        int key = ((ex >> 20) << 5) | ((ex & 0xFFFFF) >> 12);
        atomicAdd(&bcnt[key], 1);
    }
    __syncthreads();
    // hierarchical exclusive scan over 4096 bins (16 bins/thread)
    int b0 = t * 16;
    int lsum = 0;
#pragma unroll
    for (int i = 0; i < 16; ++i) lsum += bcnt[b0 + i];
    int lane = t & 63;
    int v = lsum;
#pragma unroll
    for (int d = 1; d < 64; d <<= 1) {
        int u = __shfl_up(v, d);
        if (lane >= d) v += u;
    }
    if (lane == 63) wsum[t >> 6] = v;
    __syncthreads();
    int add = 0;
    for (int i = 0; i < (t >> 6); ++i) add += wsum[i];
    int run = base + (v - lsum) + add;
#pragma unroll
    for (int i = 0; i < 16; ++i) {
        int c = bcnt[b0 + i];
        bcur[b0 + i] = run;
        run += c;
    }
    __syncthreads();
    if (t < 128) {
        int r = (b << 7) + t;
        if (r < nodes) offsets[r] = bcur[t << 5];  // row start = its first bin
    }
    __syncthreads();
    for (int j = t; j < cntE; j += 256) {
        int2 e = tmp[base + j];
        int key = ((e.x >> 20) << 5) | ((e.x & 0xFFFFF) >> 12);
        int pos = atomicAdd(&bcur[key], 1);  // LDS atomic
        int2 o;
        o.x = e.x & 0xFFFFF;
        o.y = e.y;
        edges[pos] = o;
    }
}

// ================= weight prep: fold BN, split fp32 -> bf16 hi/lo, transpose =================
__global__ void fold_split_kernel(const float* __restrict__ W, const float* __restrict__ b,
                                  const float* __restrict__ gamma, const float* __restrict__ beta,
                                  const float* __restrict__ mean, const float* __restrict__ var,
                                  unsigned short* __restrict__ WhT, unsigned short* __restrict__ WlT,
                                  float* __restrict__ bf, int K, int N) {
    int i = blockIdx.x * blockDim.x + threadIdx.x;
    if (i < K * N) {
        int k = i / N, n = i % N;
        float sc = gamma[n] * rsqrtf(var[n] + BN_EPS);
        float wf = W[i] * sc;
        unsigned short h = f2bf(wf);
        WhT[(size_t)n * K + k] = h;
        WlT[(size_t)n * K + k] = f2bf(wf - bf2f(h));
    }
    if (i < N) {
        float sc = gamma[i] * rsqrtf(var[i] + BN_EPS);
        bf[i] = (b[i] - mean[i]) * sc + beta[i];
    }
}

// W3 [K][40] -> padded transposed split [64][K]
__global__ void w3_split_kernel(const float* __restrict__ W3, unsigned short* __restrict__ WhT,
                                unsigned short* __restrict__ WlT, int K) {
    int i = blockIdx.x * blockDim.x + threadIdx.x;  // over 64*K
    if (i < 64 * K) {
        int n = i / K, k = i % K;
        float w = (n < 40) ? W3[k * 40 + n] : 0.0f;
        unsigned short h = f2bf(w);
        WhT[i] = h;
        WlT[i] = f2bf(w - bf2f(h));
    }
}

// fp32 -> bf16 elementwise (for the constant input x)
__global__ void cvt_bf16_kernel(const float* __restrict__ in, unsigned short* __restrict__ out,
                                int n) {
    int i = (blockIdx.x * blockDim.x + threadIdx.x) * 4;
    if (i < n) {
        f32x4 v = *reinterpret_cast<const f32x4*>(in + i);
        u16x4 o;
#pragma unroll
        for (int j = 0; j < 4; ++j) o[j] = f2bf(v[j]);
        *reinterpret_cast<u16x4*>(out + i) = o;
    }
}

// ================= SpMM over bf16 source (wave per row, fp32 accum, unroll-8) =================
// VW bf16 per lane (2 or 4): covers 64*VW feature columns in one pass.
template <int VW>
__global__ void spmm_bf16_kernel(const int* __restrict__ offsets, const int2* __restrict__ edges,
                                 const unsigned short* __restrict__ x, float* __restrict__ out,
                                 int sstride, int ostride, int nRows) {
    typedef float fvec __attribute__((ext_vector_type(VW)));
    int wave = threadIdx.x >> 6;
    int lane = threadIdx.x & 63;
    int r = blockIdx.x * 4 + wave;
    if (r >= nRows) return;
    int start = offsets[r], end = offsets[r + 1];
    fvec acc[4] = {};
    const unsigned short* xb = x + lane * VW;
    int j = start;
    for (; j + 7 < end; j += 8) {
        int2 e[8];
#pragma unroll
        for (int q = 0; q < 8; ++q) e[q] = edges[j + q];
        if constexpr (VW == 2) {
            unsigned u[8];
#pragma unroll
            for (int q = 0; q < 8; ++q)
                u[q] = *reinterpret_cast<const unsigned*>(xb + (size_t)e[q].x * sstride);
#pragma unroll
            for (int q = 0; q < 8; ++q) {
                float v = __int_as_float(e[q].y);
                acc[q & 3].x += v * __uint_as_float(u[q] << 16);
                acc[q & 3].y += v * __uint_as_float(u[q] & 0xFFFF0000u);
            }
        } else {
            uint2 u[8];
#pragma unroll
            for (int q = 0; q < 8; ++q)
                u[q] = *reinterpret_cast<const uint2*>(xb + (size_t)e[q].x * sstride);
#pragma unroll
            for (int q = 0; q < 8; ++q) {
                float v = __int_as_float(e[q].y);
                acc[q & 3][0] += v * __uint_as_float(u[q].x << 16);
                acc[q & 3][1] += v * __uint_as_float(u[q].x & 0xFFFF0000u);
                acc[q & 3][2] += v * __uint_as_float(u[q].y << 16);
                acc[q & 3][3] += v * __uint_as_float(u[q].y & 0xFFFF0000u);
            }
        }
    }
    for (; j < end; ++j) {
        int2 e = edges[j];
        float v = __int_as_float(e.y);
        if constexpr (VW == 2) {
            unsigned u = *reinterpret_cast<const unsigned*>(xb + (size_t)e.x * sstride);
            acc[0].x += v * __uint_as_float(u << 16);
            acc[0].y += v * __uint_as_float(u & 0xFFFF0000u);
        } else {
            uint2 u = *reinterpret_cast<const uint2*>(xb + (size_t)e.x * sstride);
            acc[0][0] += v * __uint_as_float(u.x << 16);
            acc[0][1] += v * __uint_as_float(u.x & 0xFFFF0000u);
            acc[0][2] += v * __uint_as_float(u.y << 16);
            acc[0][3] += v * __uint_as_float(u.y & 0xFFFF0000u);
        }
    }
    fvec res = (acc[0] + acc[1]) + (acc[2] + acc[3]);
    __builtin_nontemporal_store(res,
                                reinterpret_cast<fvec*>(out + (size_t)r * ostride + lane * VW));
}

// SpMM over bf16 y [nodes][64] + bias + log_softmax over first 40 lanes; NT final store
__global__ void spmm3_lsm_kernel(const int* __restrict__ offsets, const int2* __restrict__ edges,
                                 const unsigned short* __restrict__ y, const float* __restrict__ b3,
                                 float* __restrict__ out, int nRows) {
    int wave = threadIdx.x >> 6;
    int lane = threadIdx.x & 63;
    int r = blockIdx.x * 4 + wave;
    if (r >= nRows) return;
    int start = offsets[r], end = offsets[r + 1];
    float a0 = 0.f, a1 = 0.f, a2 = 0.f, a3 = 0.f;
    const unsigned short* yb = y + lane;
    int j = start;
    for (; j + 7 < end; j += 8) {
        int2 e0 = edges[j], e1 = edges[j + 1], e2 = edges[j + 2], e3 = edges[j + 3];
        int2 e4 = edges[j + 4], e5 = edges[j + 5], e6 = edges[j + 6], e7 = edges[j + 7];
        float y0 = bf2f(yb[(size_t)e0.x * 64]);
        float y1 = bf2f(yb[(size_t)e1.x * 64]);
        float y2 = bf2f(yb[(size_t)e2.x * 64]);
        float y3 = bf2f(yb[(size_t)e3.x * 64]);
        float y4 = bf2f(yb[(size_t)e4.x * 64]);
        float y5 = bf2f(yb[(size_t)e5.x * 64]);
        float y6 = bf2f(yb[(size_t)e6.x * 64]);
        float y7 = bf2f(yb[(size_t)e7.x * 64]);
        a0 += __int_as_float(e0.y) * y0;
        a1 += __int_as_float(e1.y) * y1;
        a2 += __int_as_float(e2.y) * y2;
        a3 += __int_as_float(e3.y) * y3;
        a0 += __int_as_float(e4.y) * y4;
        a1 += __int_as_float(e5.y) * y5;
        a2 += __int_as_float(e6.y) * y6;
        a3 += __int_as_float(e7.y) * y7;
    }
    for (; j < end; ++j) {
        int2 e = edges[j];
        a0 += __int_as_float(e.y) * bf2f(yb[(size_t)e.x * 64]);
    }
    float acc = (a0 + a1) + (a2 + a3);
    float val = (lane < 40) ? (acc + b3[lane]) : -INFINITY;
    float m = val;
    for (int s = 32; s >= 1; s >>= 1) m = fmaxf(m, __shfl_xor(m, s));
    float e = (lane < 40) ? expf(val - m) : 0.f;
    float sum = e;
    for (int s = 32; s >= 1; s >>= 1) sum += __shfl_xor(sum, s);
    if (lane < 40)
        __builtin_nontemporal_store(val - m - logf(sum), out + (size_t)r * 40 + lane);
}

// ================= MFMA GEMM (bf16x3 split, LDS-staged, 128x128 tile) =================
template <int K, int BN, int WM, int WN, bool RELU, bool HASBIAS, bool BF16OUT>
__global__ __launch_bounds__(256) void gemm_mfma_kernel(const float* __restrict__ A,
                                                        const unsigned short* __restrict__ BhT,
                                                        const unsigned short* __restrict__ BlT,
                                                        const float* __restrict__ bias,
                                                        void* __restrict__ Cv, int Cstride,
                                                        int nodes) {
    constexpr int BM = 128;
    constexpr int KS = 40;
    constexpr int NFM = BM / WM / 16;
    constexpr int NFN = BN / WN / 16;
    constexpr int ASL = BM * 4 / 256;
    constexpr int BSL = BN * 4 / 256;
    __shared__ unsigned short As_h[BM * KS], As_l[BM * KS];
    __shared__ unsigned short Bs_h[BN * KS], Bs_l[BN * KS];
    int t = threadIdx.x;
    int w = t >> 6, lane = t & 63;
    int wm = w % WM, wn = w / WM;
    int m0 = blockIdx.x * BM;
    int n0 = blockIdx.y * BN;
    int fr = lane & 15, fg = lane >> 4;
    f32x4 acc[NFM][NFN];
#pragma unroll
    for (int i = 0; i < NFM; ++i)
#pragma unroll
        for (int j = 0; j < NFN; ++j) acc[i][j] = f32x4{0.f, 0.f, 0.f, 0.f};

    for (int k0 = 0; k0 < K; k0 += 32) {
        f32x4 a0r[ASL], a1r[ASL];
#pragma unroll
        for (int s = 0; s < ASL; ++s) {
            int slot = t + s * 256;
            int row = slot >> 2, kb = slot & 3;
            const float* ap = A + (size_t)(m0 + row) * K + k0 + kb * 8;
            a0r[s] = *reinterpret_cast<const f32x4*>(ap);
            a1r[s] = *reinterpret_cast<const f32x4*>(ap + 4);
        }
        bf16x8 bhr[BSL], blr[BSL];
#pragma unroll
        for (int s = 0; s < BSL; ++s) {
            int slot = t + s * 256;
            int col = slot >> 2, kb = slot & 3;
            size_t off = (size_t)(n0 + col) * K + k0 + kb * 8;
            bhr[s] = *reinterpret_cast<const bf16x8*>(&BhT[off]);
            blr[s] = *reinterpret_cast<const bf16x8*>(&BlT[off]);
        }
        __syncthreads();
#pragma unroll
        for (int s = 0; s < ASL; ++s) {
            int slot = t + s * 256;
            int row = slot >> 2, kb = slot & 3;
            bf16x8 hv, lv;
#pragma unroll
            for (int j = 0; j < 4; ++j) {
                unsigned short h0 = f2bf(a0r[s][j]);
                hv[j] = (short)h0;
                lv[j] = (short)f2bf(a0r[s][j] - bf2f(h0));
                unsigned short h1 = f2bf(a1r[s][j]);
                hv[j + 4] = (short)h1;
                lv[j + 4] = (short)f2bf(a1r[s][j] - bf2f(h1));
            }
            *reinterpret_cast<bf16x8*>(&As_h[row * KS + kb * 8]) = hv;
            *reinterpret_cast<bf16x8*>(&As_l[row * KS + kb * 8]) = lv;
        }
#pragma unroll
        for (int s = 0; s < BSL; ++s) {
            int slot = t + s * 256;
            int col = slot >> 2, kb = slot & 3;
            *reinterpret_cast<bf16x8*>(&Bs_h[col * KS + kb * 8]) = bhr[s];
            *reinterpret_cast<bf16x8*>(&Bs_l[col * KS + kb * 8]) = blr[s];
        }
        __syncthreads();
        bf16x8 ah[NFM], al[NFM];
#pragma unroll
        for (int fm = 0; fm < NFM; ++fm) {
            int ar = wm * (BM / WM) + fm * 16 + fr;
            ah[fm] = *reinterpret_cast<bf16x8*>(&As_h[ar * KS + fg * 8]);
            al[fm] = *reinterpret_cast<bf16x8*>(&As_l[ar * KS + fg * 8]);
        }
#pragma unroll
        for (int fn = 0; fn < NFN; ++fn) {
            int bc = wn * (BN / WN) + fn * 16 + fr;
            bf16x8 bh = *reinterpret_cast<bf16x8*>(&Bs_h[bc * KS + fg * 8]);
            bf16x8 bl = *reinterpret_cast<bf16x8*>(&Bs_l[bc * KS + fg * 8]);
#pragma unroll
            for (int fm = 0; fm < NFM; ++fm) {
                acc[fm][fn] = __builtin_amdgcn_mfma_f32_16x16x32_bf16(ah[fm], bh, acc[fm][fn], 0, 0, 0);
                acc[fm][fn] = __builtin_amdgcn_mfma_f32_16x16x32_bf16(al[fm], bh, acc[fm][fn], 0, 0, 0);
                acc[fm][fn] = __builtin_amdgcn_mfma_f32_16x16x32_bf16(ah[fm], bl, acc[fm][fn], 0, 0, 0);
            }
        }
    }
#pragma unroll
    for (int fm = 0; fm < NFM; ++fm) {
#pragma unroll
        for (int fn = 0; fn < NFN; ++fn) {
            int col = n0 + wn * (BN / WN) + fn * 16 + fr;
            float bv = HASBIAS ? bias[col] : 0.f;
#pragma unroll
            for (int g = 0; g < 4; ++g) {
                int r = m0 + wm * (BM / WM) + fm * 16 + fg * 4 + g;
                if (r < nodes) {
                    float v = acc[fm][fn][g] + bv;
                    if (RELU) v = fmaxf(v, 0.f);
                    if (BF16OUT)
                        ((unsigned short*)Cv)[(size_t)r * Cstride + col] = f2bf(v);
                    else
                        ((float*)Cv)[(size_t)r * Cstride + col] = v;
                }
            }
        }
    }
}

// ================= launch =================
extern "C" void kernel_launch(void* const* d_in, const int* in_sizes, int n_in,
                              void* d_out, int out_size, void* d_ws, size_t ws_size,
                              hipStream_t stream) {
    const float* x = (const float*)d_in[0];
    const int* erow = (const int*)d_in[1];
    const int* ecol = (const int*)d_in[2];
    const float* evals = (const float*)d_in[3];
    const float* W1 = (const float*)d_in[4];
    const float* b1 = (const float*)d_in[5];
    const float* W2 = (const float*)d_in[6];
    const float* b2 = (const float*)d_in[7];
    const float* W3 = (const float*)d_in[8];
    const float* b3 = (const float*)d_in[9];
    const float* gamma1 = (const float*)d_in[10];
    const float* beta1 = (const float*)d_in[11];
    const float* mean1 = (const float*)d_in[12];
    const float* var1 = (const float*)d_in[13];
    const float* gamma2 = (const float*)d_in[14];
    const float* beta2 = (const float*)d_in[15];
    const float* mean2 = (const float*)d_in[16];
    const float* var2 = (const float*)d_in[17];
    float* out = (float*)d_out;

    int nodes = in_sizes[0] / 128;
    int nE = in_sizes[1];
    int padRows = (nodes + 127) & ~127;  // 128-multiple for the GEMM tile
    int nB2 = (nodes + 127) >> 7;        // coarse buckets of 128 rows

    char* p = (char*)d_ws;
    auto carve = [&](size_t bytes) {
        void* r = (void*)p;
        p += (bytes + 255) & ~(size_t)255;
        return r;
    };
    int* offsets = (int*)carve((size_t)(nodes + 1) * 4);
    int* blockCounts = (int*)carve((size_t)B1 * nB2 * 4);
    int* bucketTotal = (int*)carve((size_t)nB2 * 4);
    int* bucketBase = (int*)carve((size_t)(nB2 + 1) * 4);
    int2* edges = (int2*)carve((size_t)nE * 8);
    unsigned short* WhT1 = (unsigned short*)carve(256 * 128 * 2);
    unsigned short* WlT1 = (unsigned short*)carve(256 * 128 * 2);
    unsigned short* WhT2 = (unsigned short*)carve(256 * 256 * 2);
    unsigned short* WlT2 = (unsigned short*)carve(256 * 256 * 2);
    unsigned short* WhT3 = (unsigned short*)carve(64 * 256 * 2);
    unsigned short* WlT3 = (unsigned short*)carve(64 * 256 * 2);
    float* b1f = (float*)carve(256 * 4);
    float* b2f = (float*)carve(256 * 4);
    float* bufA = (float*)carve((size_t)padRows * 256 * 4);
    float* bufB = (float*)carve((size_t)padRows * 256 * 4);
    // aliases (sequential lifetimes):
    int2* tmp = (int2*)bufA;                    // CSR staging; dead before spmm1 writes bufA
    unsigned short* xb16 = (unsigned short*)bufB;   // x bf16 [nodes][128]; dead after spmm1
    unsigned short* z1b16 = (unsigned short*)bufB;  // z1 bf16 [nodes][256]; dead when gemm2 writes z2->bufB
    unsigned short* y16 = (unsigned short*)bufA;    // y bf16 [padRows][64]; written after h2 (bufA) dies

    // ---- CSR build: count -> scan -> scatter -> per-bucket col-block sort ----
    int chunk = (nE + B1 - 1) / B1;
    count_kernel<<<B1, 256, 0, stream>>>(erow, blockCounts, nB2, nE, chunk);
    scan_buckets_kernel<<<nB2, 256, 0, stream>>>(blockCounts, bucketTotal, nB2);
    scan_total_kernel<<<1, 256, 0, stream>>>(bucketTotal, bucketBase, offsets, nB2, nodes);
    scatter2_kernel<<<B1, 256, 0, stream>>>(erow, ecol, evals, blockCounts, bucketBase, tmp, nB2,
                                            nE, chunk);
    bucket_sort2_kernel<<<nB2, 256, 0, stream>>>(bucketBase, tmp, edges, offsets, nodes);

    // ---- weight prep: fold BN + bf16 hi/lo split + transpose ----
    fold_split_kernel<<<(128 * 256 + 255) / 256, 256, 0, stream>>>(
        W1, b1, gamma1, beta1, mean1, var1, WhT1, WlT1, b1f, 128, 256);
    fold_split_kernel<<<(256 * 256 + 255) / 256, 256, 0, stream>>>(
        W2, b2, gamma2, beta2, mean2, var2, WhT2, WlT2, b2f, 256, 256);
    w3_split_kernel<<<(64 * 256 + 255) / 256, 256, 0, stream>>>(W3, WhT3, WlT3, 256);

    // ---- pipeline ----
    int gR = (nodes + 3) / 4;
    int gM = padRows / 128;

    // x -> bf16 (gather source for layer 1)
    int nX = nodes * 128;
    cvt_bf16_kernel<<<(nX / 4 + 255) / 256, 256, 0, stream>>>(x, xb16, nX);
    // layer 1: h = A*x_bf16 ; z1(bf16) = relu(h @ W1' + b1')
    spmm_bf16_kernel<2><<<gR, 256, 0, stream>>>(offsets, edges, xb16, bufA, 128, 128, nodes);
    gemm_mfma_kernel<128, 128, 2, 2, true, true, true><<<dim3(gM, 2), 256, 0, stream>>>(
        bufA, WhT1, WlT1, b1f, z1b16, 256, nodes);
    // layer 2: h2 = A*z1_bf16 (single 256-col pass); z2(fp32) = relu(h2 @ W2' + b2')
    spmm_bf16_kernel<4><<<gR, 256, 0, stream>>>(offsets, edges, z1b16, bufA, 256, 256, nodes);
    gemm_mfma_kernel<256, 128, 2, 2, true, true, false><<<dim3(gM, 2), 256, 0, stream>>>(
        bufA, WhT2, WlT2, b2f, bufB, 256, nodes);
    // layer 3 (reassociated): y(bf16) = z2 @ W3 (padded 64 cols); out = logsoftmax(A*y + b3)
    gemm_mfma_kernel<256, 64, 4, 1, false, false, true><<<dim3(gM, 1), 256, 0, stream>>>(
        bufB, WhT3, WlT3, nullptr, y16, 64, nodes);
    spmm3_lsm_kernel<<<gR, 256, 0, stream>>>(offsets, edges, y16, b3, out, nodes);
}

// Round 17
// 687.552 us; speedup vs baseline: 1.1435x; 1.1435x over previous
//
#include <hip/hip_runtime.h>
#include <hip/hip_bf16.h>
#include <math.h>

#define BN_EPS 1e-5f
#define B1 256      // edge-chunk blocks for count/scatter passes (must == blockDim)
#define MAXNB 1024  // max coarse buckets (128 rows each); 100k nodes -> 782

typedef float f32x4 __attribute__((ext_vector_type(4)));
typedef float f32x2 __attribute__((ext_vector_type(2)));
typedef short bf16x8 __attribute__((ext_vector_type(8)));
typedef unsigned short u16x4 __attribute__((ext_vector_type(4)));

__device__ inline unsigned short f2bf(float v) {
    unsigned b = __float_as_uint(v);
    unsigned r = (b + 0x7FFFu + ((b >> 16) & 1u)) >> 16;
    return (unsigned short)r;
}
__device__ inline float bf2f(unsigned short h) {
    return __uint_as_float(((unsigned)h) << 16);
}

// ================= CSR build (atomic-free at global scope) =================
__global__ __launch_bounds__(256) void count_kernel(const int* __restrict__ row,
                                                    int* __restrict__ blockCounts,
                                                    int nB2, int nE, int chunk) {
    __shared__ int hist[MAXNB];
    int t = threadIdx.x;
    for (int b = t; b < nB2; b += 256) hist[b] = 0;
    __syncthreads();
    int s0 = blockIdx.x * chunk;
    int s1 = s0 + chunk;
    if (s1 > nE) s1 = nE;
    for (int j = s0 + t; j < s1; j += 256) atomicAdd(&hist[row[j] >> 7], 1);
    __syncthreads();
    for (int b = t; b < nB2; b += 256) blockCounts[blockIdx.x * nB2 + b] = hist[b];
}

__global__ __launch_bounds__(256) void scan_buckets_kernel(int* __restrict__ blockCounts,
                                                           int* __restrict__ bucketTotal,
                                                           int nB2) {
    int b = blockIdx.x;
    int t = threadIdx.x;
    int lane = t & 63;
    int s = blockCounts[t * nB2 + b];
    int v = s;
#pragma unroll
    for (int d = 1; d < 64; d <<= 1) {
        int u = __shfl_up(v, d);
        if (lane >= d) v += u;
    }
    __shared__ int ws[4];
    if (lane == 63) ws[t >> 6] = v;
    __syncthreads();
    int add = 0;
    for (int i = 0; i < (t >> 6); ++i) add += ws[i];
    v += add;
    blockCounts[t * nB2 + b] = v - s;  // exclusive within bucket
    if (t == 255) bucketTotal[b] = v;
}

__global__ __launch_bounds__(256) void scan_total_kernel(const int* __restrict__ bucketTotal,
                                                         int* __restrict__ bucketBase,
                                                         int* __restrict__ offsets,
                                                         int nB2, int nodes) {
    int t = threadIdx.x;
    int lane = t & 63;
    int b0 = t * 4;
    int c0 = (b0 + 0 < nB2) ? bucketTotal[b0 + 0] : 0;
    int c1 = (b0 + 1 < nB2) ? bucketTotal[b0 + 1] : 0;
    int c2 = (b0 + 2 < nB2) ? bucketTotal[b0 + 2] : 0;
    int c3 = (b0 + 3 < nB2) ? bucketTotal[b0 + 3] : 0;
    int s = c0 + c1 + c2 + c3;
    int v = s;
#pragma unroll
    for (int d = 1; d < 64; d <<= 1) {
        int u = __shfl_up(v, d);
        if (lane >= d) v += u;
    }
    __shared__ int ws[4];
    if (lane == 63) ws[t >> 6] = v;
    __syncthreads();
    int add = 0;
    for (int i = 0; i < (t >> 6); ++i) add += ws[i];
    v += add;
    int p = v - s;
    if (b0 + 0 <= nB2) bucketBase[b0 + 0] = p; p += c0;
    if (b0 + 1 <= nB2) bucketBase[b0 + 1] = p; p += c1;
    if (b0 + 2 <= nB2) bucketBase[b0 + 2] = p; p += c2;
    if (b0 + 3 <= nB2) bucketBase[b0 + 3] = p;
    if (t == 255) offsets[nodes] = v;  // grand total == nE
}

__global__ __launch_bounds__(256) void scatter2_kernel(const int* __restrict__ row,
                                                       const int* __restrict__ col,
                                                       const float* __restrict__ val,
                                                       const int* __restrict__ blockCounts,
                                                       const int* __restrict__ bucketBase,
                                                       int2* __restrict__ tmp,
                                                       int nB2, int nE, int chunk) {
    __shared__ int cur[MAXNB];
    int t = threadIdx.x;
    for (int b = t; b < nB2; b += 256)
        cur[b] = bucketBase[b] + blockCounts[blockIdx.x * nB2 + b];
    __syncthreads();
    int s0 = blockIdx.x * chunk;
    int s1 = s0 + chunk;
    if (s1 > nE) s1 = nE;
    for (int j = s0 + t; j < s1; j += 256) {
        int r = row[j];
        int p = atomicAdd(&cur[r >> 7], 1);  // LDS atomic
        int2 e;
        e.x = col[j] | ((r & 127) << 20);
        e.y = __float_as_int(val[j]);
        tmp[p] = e;
    }
}

// Pass 3: one block per 128-row bucket; LDS histogram + 2-wave scan -> row
// offsets, then re-scatter into final CSR order (dest = bucket's ~32KB window).
__global__ __launch_bounds__(256) void bucket_sort2_kernel(const int* __restrict__ bucketBase,
                                                           const int2* __restrict__ tmp,
                                                           int2* __restrict__ edges,
                                                           int* __restrict__ offsets,
                                                           int nodes) {
    __shared__ int rcnt[128];
    __shared__ int rcur[128];
    __shared__ int w0sum;
    int b = blockIdx.x;
    int t = threadIdx.x;
    int base = bucketBase[b];
    int cntE = bucketBase[b + 1] - base;
    if (t < 128) rcnt[t] = 0;
    __syncthreads();
    for (int j = t; j < cntE; j += 256) atomicAdd(&rcnt[tmp[base + j].x >> 20], 1);
    __syncthreads();
    int s = 0, v = 0;
    if (t < 128) {
        s = rcnt[t];
        v = s;
        int lane = t & 63;
#pragma unroll
        for (int d = 1; d < 64; d <<= 1) {
            int u = __shfl_up(v, d);
            if (lane >= d) v += u;
        }
        if (t == 63) w0sum = v;
    }
    __syncthreads();
    if (t < 128) {
        int excl = v - s + ((t >= 64) ? w0sum : 0);
        rcur[t] = base + excl;
        int r = (b << 7) + t;
        if (r < nodes) offsets[r] = base + excl;
    }
    __syncthreads();
    for (int j = t; j < cntE; j += 256) {
        int2 e = tmp[base + j];
        int pos = atomicAdd(&rcur[e.x >> 20], 1);  // LDS atomic
        int2 o;
        o.x = e.x & 0xFFFFF;
        o.y = e.y;
        edges[pos] = o;
    }
}

// ================= weight prep: fold BN, split fp32 -> bf16 hi/lo, transpose =================
__global__ void fold_split_kernel(const float* __restrict__ W, const float* __restrict__ b,
                                  const float* __restrict__ gamma, const float* __restrict__ beta,
                                  const float* __restrict__ mean, const float* __restrict__ var,
                                  unsigned short* __restrict__ WhT, unsigned short* __restrict__ WlT,
                                  float* __restrict__ bf, int K, int N) {
    int i = blockIdx.x * blockDim.x + threadIdx.x;
    if (i < K * N) {
        int k = i / N, n = i % N;
        float sc = gamma[n] * rsqrtf(var[n] + BN_EPS);
        float wf = W[i] * sc;
        unsigned short h = f2bf(wf);
        WhT[(size_t)n * K + k] = h;
        WlT[(size_t)n * K + k] = f2bf(wf - bf2f(h));
    }
    if (i < N) {
        float sc = gamma[i] * rsqrtf(var[i] + BN_EPS);
        bf[i] = (b[i] - mean[i]) * sc + beta[i];
    }
}

// W3 [K][40] -> padded transposed split [64][K]
__global__ void w3_split_kernel(const float* __restrict__ W3, unsigned short* __restrict__ WhT,
                                unsigned short* __restrict__ WlT, int K) {
    int i = blockIdx.x * blockDim.x + threadIdx.x;  // over 64*K
    if (i < 64 * K) {
        int n = i / K, k = i % K;
        float w = (n < 40) ? W3[k * 40 + n] : 0.0f;
        unsigned short h = f2bf(w);
        WhT[i] = h;
        WlT[i] = f2bf(w - bf2f(h));
    }
}

// fp32 -> bf16 elementwise (for the constant input x)
__global__ void cvt_bf16_kernel(const float* __restrict__ in, unsigned short* __restrict__ out,
                                int n) {
    int i = (blockIdx.x * blockDim.x + threadIdx.x) * 4;
    if (i < n) {
        f32x4 v = *reinterpret_cast<const f32x4*>(in + i);
        u16x4 o;
#pragma unroll
        for (int j = 0; j < 4; ++j) o[j] = f2bf(v[j]);
        *reinterpret_cast<u16x4*>(out + i) = o;
    }
}

// ================= SpMM over bf16 source (wave per row, fp32 accum, unroll-8) =================
// VW bf16 per lane (2 or 4). Output bf16 (NT store) — consumed by A16 GEMM.
template <int VW>
__global__ void spmm_bf16_kernel(const int* __restrict__ offsets, const int2* __restrict__ edges,
                                 const unsigned short* __restrict__ x,
                                 unsigned short* __restrict__ out,
                                 int sstride, int ostride, int nRows) {
    typedef float fvec __attribute__((ext_vector_type(VW)));
    int wave = threadIdx.x >> 6;
    int lane = threadIdx.x & 63;
    int r = blockIdx.x * 4 + wave;
    if (r >= nRows) return;
    int start = offsets[r], end = offsets[r + 1];
    fvec acc[4] = {};
    const unsigned short* xb = x + lane * VW;
    int j = start;
    for (; j + 7 < end; j += 8) {
        int2 e[8];
#pragma unroll
        for (int q = 0; q < 8; ++q) e[q] = edges[j + q];
        if constexpr (VW == 2) {
            unsigned u[8];
#pragma unroll
            for (int q = 0; q < 8; ++q)
                u[q] = *reinterpret_cast<const unsigned*>(xb + (size_t)e[q].x * sstride);
#pragma unroll
            for (int q = 0; q < 8; ++q) {
                float v = __int_as_float(e[q].y);
                acc[q & 3].x += v * __uint_as_float(u[q] << 16);
                acc[q & 3].y += v * __uint_as_float(u[q] & 0xFFFF0000u);
            }
        } else {
            uint2 u[8];
#pragma unroll
            for (int q = 0; q < 8; ++q)
                u[q] = *reinterpret_cast<const uint2*>(xb + (size_t)e[q].x * sstride);
#pragma unroll
            for (int q = 0; q < 8; ++q) {
                float v = __int_as_float(e[q].y);
                acc[q & 3][0] += v * __uint_as_float(u[q].x << 16);
                acc[q & 3][1] += v * __uint_as_float(u[q].x & 0xFFFF0000u);
                acc[q & 3][2] += v * __uint_as_float(u[q].y << 16);
                acc[q & 3][3] += v * __uint_as_float(u[q].y & 0xFFFF0000u);
            }
        }
    }
    for (; j < end; ++j) {
        int2 e = edges[j];
        float v = __int_as_float(e.y);
        if constexpr (VW == 2) {
            unsigned u = *reinterpret_cast<const unsigned*>(xb + (size_t)e.x * sstride);
            acc[0].x += v * __uint_as_float(u << 16);
            acc[0].y += v * __uint_as_float(u & 0xFFFF0000u);
        } else {
            uint2 u = *reinterpret_cast<const uint2*>(xb + (size_t)e.x * sstride);
            acc[0][0] += v * __uint_as_float(u.x << 16);
            acc[0][1] += v * __uint_as_float(u.x & 0xFFFF0000u);
            acc[0][2] += v * __uint_as_float(u.y << 16);
            acc[0][3] += v * __uint_as_float(u.y & 0xFFFF0000u);
        }
    }
    fvec res = (acc[0] + acc[1]) + (acc[2] + acc[3]);
    if constexpr (VW == 2) {
        unsigned o = (unsigned)f2bf(res.x) | ((unsigned)f2bf(res.y) << 16);
        __builtin_nontemporal_store(o,
            reinterpret_cast<unsigned*>(out + (size_t)r * ostride + lane * 2));
    } else {
        u16x4 o;
#pragma unroll
        for (int q = 0; q < 4; ++q) o[q] = f2bf(res[q]);
        __builtin_nontemporal_store(o,
            reinterpret_cast<u16x4*>(out + (size_t)r * ostride + lane * 4));
    }
}

// SpMM over bf16 y [nodes][64] + bias + log_softmax over first 40 lanes; NT final store
__global__ void spmm3_lsm_kernel(const int* __restrict__ offsets, const int2* __restrict__ edges,
                                 const unsigned short* __restrict__ y, const float* __restrict__ b3,
                                 float* __restrict__ out, int nRows) {
    int wave = threadIdx.x >> 6;
    int lane = threadIdx.x & 63;
    int r = blockIdx.x * 4 + wave;
    if (r >= nRows) return;
    int start = offsets[r], end = offsets[r + 1];
    float a0 = 0.f, a1 = 0.f, a2 = 0.f, a3 = 0.f;
    const unsigned short* yb = y + lane;
    int j = start;
    for (; j + 7 < end; j += 8) {
        int2 e0 = edges[j], e1 = edges[j + 1], e2 = edges[j + 2], e3 = edges[j + 3];
        int2 e4 = edges[j + 4], e5 = edges[j + 5], e6 = edges[j + 6], e7 = edges[j + 7];
        float y0 = bf2f(yb[(size_t)e0.x * 64]);
        float y1 = bf2f(yb[(size_t)e1.x * 64]);
        float y2 = bf2f(yb[(size_t)e2.x * 64]);
        float y3 = bf2f(yb[(size_t)e3.x * 64]);
        float y4 = bf2f(yb[(size_t)e4.x * 64]);
        float y5 = bf2f(yb[(size_t)e5.x * 64]);
        float y6 = bf2f(yb[(size_t)e6.x * 64]);
        float y7 = bf2f(yb[(size_t)e7.x * 64]);
        a0 += __int_as_float(e0.y) * y0;
        a1 += __int_as_float(e1.y) * y1;
        a2 += __int_as_float(e2.y) * y2;
        a3 += __int_as_float(e3.y) * y3;
        a0 += __int_as_float(e4.y) * y4;
        a1 += __int_as_float(e5.y) * y5;
        a2 += __int_as_float(e6.y) * y6;
        a3 += __int_as_float(e7.y) * y7;
    }
    for (; j < end; ++j) {
        int2 e = edges[j];
        a0 += __int_as_float(e.y) * bf2f(yb[(size_t)e.x * 64]);
    }
    float acc = (a0 + a1) + (a2 + a3);
    float val = (lane < 40) ? (acc + b3[lane]) : -INFINITY;
    float m = val;
    for (int s = 32; s >= 1; s >>= 1) m = fmaxf(m, __shfl_xor(m, s));
    float e = (lane < 40) ? expf(val - m) : 0.f;
    float sum = e;
    for (int s = 32; s >= 1; s >>= 1) sum += __shfl_xor(sum, s);
    if (lane < 40)
        __builtin_nontemporal_store(val - m - logf(sum), out + (size_t)r * 40 + lane);
}

// ================= MFMA GEMM (A bf16, W bf16x2 split; LDS-staged 128xBN tile) =================
// C = A16 @ (Wh + Wl) (+bias, relu): 2 MFMAs per B-fragment pair (no A split).
// A bf16 [M][K]; WhT/WlT [N][K] bf16. One A panel in LDS (30KB total for BN=128).
template <int K, int BN, int WM, int WN, bool RELU, bool HASBIAS, bool BF16OUT>
__global__ __launch_bounds__(256) void gemm_a16_kernel(const unsigned short* __restrict__ A,
                                                       const unsigned short* __restrict__ BhT,
                                                       const unsigned short* __restrict__ BlT,
                                                       const float* __restrict__ bias,
                                                       void* __restrict__ Cv, int Cstride,
                                                       int nodes) {
    constexpr int BM = 128;
    constexpr int KS = 40;
    constexpr int NFM = BM / WM / 16;
    constexpr int NFN = BN / WN / 16;
    constexpr int ASL = BM * 4 / 256;  // = 2
    constexpr int BSL = BN * 4 / 256;  // 2 (BN=128) or 1 (BN=64)
    __shared__ unsigned short As[BM * KS];
    __shared__ unsigned short Bs_h[BN * KS], Bs_l[BN * KS];
    int t = threadIdx.x;
    int w = t >> 6, lane = t & 63;
    int wm = w % WM, wn = w / WM;
    int m0 = blockIdx.x * BM;
    int n0 = blockIdx.y * BN;
    int fr = lane & 15, fg = lane >> 4;
    f32x4 acc[NFM][NFN];
#pragma unroll
    for (int i = 0; i < NFM; ++i)
#pragma unroll
        for (int j = 0; j < NFN; ++j) acc[i][j] = f32x4{0.f, 0.f, 0.f, 0.f};

    for (int k0 = 0; k0 < K; k0 += 32) {
        bf16x8 ar[ASL];
#pragma unroll
        for (int s = 0; s < ASL; ++s) {
            int slot = t + s * 256;
            int row = slot >> 2, kb = slot & 3;
            ar[s] = *reinterpret_cast<const bf16x8*>(&A[(size_t)(m0 + row) * K + k0 + kb * 8]);
        }
        bf16x8 bhr[BSL], blr[BSL];
#pragma unroll
        for (int s = 0; s < BSL; ++s) {
            int slot = t + s * 256;
            int col = slot >> 2, kb = slot & 3;
            size_t off = (size_t)(n0 + col) * K + k0 + kb * 8;
            bhr[s] = *reinterpret_cast<const bf16x8*>(&BhT[off]);
            blr[s] = *reinterpret_cast<const bf16x8*>(&BlT[off]);
        }
        __syncthreads();  // prev-iter LDS reads done
#pragma unroll
        for (int s = 0; s < ASL; ++s) {
            int slot = t + s * 256;
            int row = slot >> 2, kb = slot & 3;
            *reinterpret_cast<bf16x8*>(&As[row * KS + kb * 8]) = ar[s];
        }
#pragma unroll
        for (int s = 0; s < BSL; ++s) {
            int slot = t + s * 256;
            int col = slot >> 2, kb = slot & 3;
            *reinterpret_cast<bf16x8*>(&Bs_h[col * KS + kb * 8]) = bhr[s];
            *reinterpret_cast<bf16x8*>(&Bs_l[col * KS + kb * 8]) = blr[s];
        }
        __syncthreads();  // LDS ready
        bf16x8 af[NFM];
#pragma unroll
        for (int fm = 0; fm < NFM; ++fm) {
            int arow = wm * (BM / WM) + fm * 16 + fr;
            af[fm] = *reinterpret_cast<bf16x8*>(&As[arow * KS + fg * 8]);
        }
#pragma unroll
        for (int fn = 0; fn < NFN; ++fn) {
            int bc = wn * (BN / WN) + fn * 16 + fr;
            bf16x8 bh = *reinterpret_cast<bf16x8*>(&Bs_h[bc * KS + fg * 8]);
            bf16x8 bl = *reinterpret_cast<bf16x8*>(&Bs_l[bc * KS + fg * 8]);
#pragma unroll
            for (int fm = 0; fm < NFM; ++fm) {
                acc[fm][fn] = __builtin_amdgcn_mfma_f32_16x16x32_bf16(af[fm], bh, acc[fm][fn], 0, 0, 0);
                acc[fm][fn] = __builtin_amdgcn_mfma_f32_16x16x32_bf16(af[fm], bl, acc[fm][fn], 0, 0, 0);
            }
        }
    }
    // epilogue: C/D mapping col = lane&15, row = (lane>>4)*4 + reg
#pragma unroll
    for (int fm = 0; fm < NFM; ++fm) {
#pragma unroll
        for (int fn = 0; fn < NFN; ++fn) {
            int col = n0 + wn * (BN / WN) + fn * 16 + fr;
            float bv = HASBIAS ? bias[col] : 0.f;
#pragma unroll
            for (int g = 0; g < 4; ++g) {
                int r = m0 + wm * (BM / WM) + fm * 16 + fg * 4 + g;
                if (r < nodes) {
                    float v = acc[fm][fn][g] + bv;
                    if (RELU) v = fmaxf(v, 0.f);
                    if (BF16OUT)
                        ((unsigned short*)Cv)[(size_t)r * Cstride + col] = f2bf(v);
                    else
                        ((float*)Cv)[(size_t)r * Cstride + col] = v;
                }
            }
        }
    }
}

// ================= launch =================
extern "C" void kernel_launch(void* const* d_in, const int* in_sizes, int n_in,
                              void* d_out, int out_size, void* d_ws, size_t ws_size,
                              hipStream_t stream) {
    const float* x = (const float*)d_in[0];
    const int* erow = (const int*)d_in[1];
    const int* ecol = (const int*)d_in[2];
    const float* evals = (const float*)d_in[3];
    const float* W1 = (const float*)d_in[4];
    const float* b1 = (const float*)d_in[5];
    const float* W2 = (const float*)d_in[6];
    const float* b2 = (const float*)d_in[7];
    const float* W3 = (const float*)d_in[8];
    const float* b3 = (const float*)d_in[9];
    const float* gamma1 = (const float*)d_in[10];
    const float* beta1 = (const float*)d_in[11];
    const float* mean1 = (const float*)d_in[12];
    const float* var1 = (const float*)d_in[13];
    const float* gamma2 = (const float*)d_in[14];
    const float* beta2 = (const float*)d_in[15];
    const float* mean2 = (const float*)d_in[16];
    const float* var2 = (const float*)d_in[17];
    float* out = (float*)d_out;

    int nodes = in_sizes[0] / 128;
    int nE = in_sizes[1];
    int padRows = (nodes + 127) & ~127;  // 128-multiple for the GEMM tile
    int nB2 = (nodes + 127) >> 7;        // coarse buckets of 128 rows

    char* p = (char*)d_ws;
    auto carve = [&](size_t bytes) {
        void* r = (void*)p;
        p += (bytes + 255) & ~(size_t)255;
        return r;
    };
    int* offsets = (int*)carve((size_t)(nodes + 1) * 4);
    int* blockCounts = (int*)carve((size_t)B1 * nB2 * 4);
    int* bucketTotal = (int*)carve((size_t)nB2 * 4);
    int* bucketBase = (int*)carve((size_t)(nB2 + 1) * 4);
    int2* edges = (int2*)carve((size_t)nE * 8);
    unsigned short* WhT1 = (unsigned short*)carve(256 * 128 * 2);
    unsigned short* WlT1 = (unsigned short*)carve(256 * 128 * 2);
    unsigned short* WhT2 = (unsigned short*)carve(256 * 256 * 2);
    unsigned short* WlT2 = (unsigned short*)carve(256 * 256 * 2);
    unsigned short* WhT3 = (unsigned short*)carve(64 * 256 * 2);
    unsigned short* WlT3 = (unsigned short*)carve(64 * 256 * 2);
    float* b1f = (float*)carve(256 * 4);
    float* b2f = (float*)carve(256 * 4);
    float* bufA = (float*)carve((size_t)padRows * 256 * 4);
    float* bufB = (float*)carve((size_t)padRows * 256 * 4);
    // aliases (sequential lifetimes, all bf16 now):
    int2* tmp = (int2*)bufA;                        // CSR staging; dead before spmm1 writes h16
    unsigned short* xb16 = (unsigned short*)bufB;   // x bf16 [nodes][128]; dead after spmm1
    unsigned short* h16 = (unsigned short*)bufA;    // h bf16 [padRows][128]; dead after gemm1
    unsigned short* z1b16 = (unsigned short*)bufB;  // z1 bf16 [nodes][256]; dead after spmm2
    unsigned short* h2b16 = (unsigned short*)bufA;  // h2 bf16 [padRows][256]; dead after gemm2
    unsigned short* z2b16 = (unsigned short*)bufB;  // z2 bf16 [padRows][256]; dead after gemm3
    unsigned short* y16 = (unsigned short*)bufA;    // y bf16 [padRows][64]; after h2 dies

    // ---- CSR build: count -> scan -> scatter -> per-bucket sort (no global atomics) ----
    int chunk = (nE + B1 - 1) / B1;
    count_kernel<<<B1, 256, 0, stream>>>(erow, blockCounts, nB2, nE, chunk);
    scan_buckets_kernel<<<nB2, 256, 0, stream>>>(blockCounts, bucketTotal, nB2);
    scan_total_kernel<<<1, 256, 0, stream>>>(bucketTotal, bucketBase, offsets, nB2, nodes);
    scatter2_kernel<<<B1, 256, 0, stream>>>(erow, ecol, evals, blockCounts, bucketBase, tmp, nB2,
                                            nE, chunk);
    bucket_sort2_kernel<<<nB2, 256, 0, stream>>>(bucketBase, tmp, edges, offsets, nodes);

    // ---- weight prep: fold BN + bf16 hi/lo split + transpose ----
    fold_split_kernel<<<(128 * 256 + 255) / 256, 256, 0, stream>>>(
        W1, b1, gamma1, beta1, mean1, var1, WhT1, WlT1, b1f, 128, 256);
    fold_split_kernel<<<(256 * 256 + 255) / 256, 256, 0, stream>>>(
        W2, b2, gamma2, beta2, mean2, var2, WhT2, WlT2, b2f, 256, 256);
    w3_split_kernel<<<(64 * 256 + 255) / 256, 256, 0, stream>>>(W3, WhT3, WlT3, 256);

    // ---- pipeline ----
    int gR = (nodes + 3) / 4;
    int gM = padRows / 128;

    // x -> bf16 (gather source for layer 1)
    int nX = nodes * 128;
    cvt_bf16_kernel<<<(nX / 4 + 255) / 256, 256, 0, stream>>>(x, xb16, nX);
    // layer 1: h(bf16) = A*x_bf16 ; z1(bf16) = relu(h @ W1' + b1')
    spmm_bf16_kernel<2><<<gR, 256, 0, stream>>>(offsets, edges, xb16, h16, 128, 128, nodes);
    gemm_a16_kernel<128, 128, 2, 2, true, true, true><<<dim3(gM, 2), 256, 0, stream>>>(
        h16, WhT1, WlT1, b1f, z1b16, 256, nodes);
    // layer 2: h2(bf16) = A*z1 (single 256-col pass); z2(bf16) = relu(h2 @ W2' + b2')
    spmm_bf16_kernel<4><<<gR, 256, 0, stream>>>(offsets, edges, z1b16, h2b16, 256, 256, nodes);
    gemm_a16_kernel<256, 128, 2, 2, true, true, true><<<dim3(gM, 2), 256, 0, stream>>>(
        h2b16, WhT2, WlT2, b2f, z2b16, 256, nodes);
    // layer 3 (reassociated): y(bf16) = z2 @ W3 (padded 64 cols); out = logsoftmax(A*y + b3)
    gemm_a16_kernel<256, 64, 4, 1, false, false, true><<<dim3(gM, 1), 256, 0, stream>>>(
        z2b16, WhT3, WlT3, nullptr, y16, 64, nodes);
    spmm3_lsm_kernel<<<gR, 256, 0, stream>>>(offsets, edges, y16, b3, out, nodes);
}

// Round 18
// 556.812 us; speedup vs baseline: 1.4120x; 1.2348x over previous
//
#include <hip/hip_runtime.h>
#include <hip/hip_bf16.h>
#include <math.h>

#define BN_EPS 1e-5f
#define B1 256      // edge-chunk blocks for count/scatter passes (must == blockDim)
#define MAXNB 1024  // max coarse buckets (128 rows each); 100k nodes -> 782

typedef float f32x4 __attribute__((ext_vector_type(4)));
typedef float f32x2 __attribute__((ext_vector_type(2)));
typedef short bf16x8 __attribute__((ext_vector_type(8)));
typedef unsigned short u16x4 __attribute__((ext_vector_type(4)));

__device__ inline unsigned short f2bf(float v) {
    unsigned b = __float_as_uint(v);
    unsigned r = (b + 0x7FFFu + ((b >> 16) & 1u)) >> 16;
    return (unsigned short)r;
}
__device__ inline float bf2f(unsigned short h) {
    return __uint_as_float(((unsigned)h) << 16);
}

// ================= CSR build (atomic-free at global scope) =================
__global__ __launch_bounds__(256) void count_kernel(const int* __restrict__ row,
                                                    int* __restrict__ blockCounts,
                                                    int nB2, int nE, int chunk) {
    __shared__ int hist[MAXNB];
    int t = threadIdx.x;
    for (int b = t; b < nB2; b += 256) hist[b] = 0;
    __syncthreads();
    int s0 = blockIdx.x * chunk;
    int s1 = s0 + chunk;
    if (s1 > nE) s1 = nE;
    for (int j = s0 + t; j < s1; j += 256) atomicAdd(&hist[row[j] >> 7], 1);
    __syncthreads();
    for (int b = t; b < nB2; b += 256) blockCounts[blockIdx.x * nB2 + b] = hist[b];
}

__global__ __launch_bounds__(256) void scan_buckets_kernel(int* __restrict__ blockCounts,
                                                           int* __restrict__ bucketTotal,
                                                           int nB2) {
    int b = blockIdx.x;
    int t = threadIdx.x;
    int lane = t & 63;
    int s = blockCounts[t * nB2 + b];
    int v = s;
#pragma unroll
    for (int d = 1; d < 64; d <<= 1) {
        int u = __shfl_up(v, d);
        if (lane >= d) v += u;
    }
    __shared__ int ws[4];
    if (lane == 63) ws[t >> 6] = v;
    __syncthreads();
    int add = 0;
    for (int i = 0; i < (t >> 6); ++i) add += ws[i];
    v += add;
    blockCounts[t * nB2 + b] = v - s;  // exclusive within bucket
    if (t == 255) bucketTotal[b] = v;
}

__global__ __launch_bounds__(256) void scan_total_kernel(const int* __restrict__ bucketTotal,
                                                         int* __restrict__ bucketBase,
                                                         int* __restrict__ offsets,
                                                         int nB2, int nodes) {
    int t = threadIdx.x;
    int lane = t & 63;
    int b0 = t * 4;
    int c0 = (b0 + 0 < nB2) ? bucketTotal[b0 + 0] : 0;
    int c1 = (b0 + 1 < nB2) ? bucketTotal[b0 + 1] : 0;
    int c2 = (b0 + 2 < nB2) ? bucketTotal[b0 + 2] : 0;
    int c3 = (b0 + 3 < nB2) ? bucketTotal[b0 + 3] : 0;
    int s = c0 + c1 + c2 + c3;
    int v = s;
#pragma unroll
    for (int d = 1; d < 64; d <<= 1) {
        int u = __shfl_up(v, d);
        if (lane >= d) v += u;
    }
    __shared__ int ws[4];
    if (lane == 63) ws[t >> 6] = v;
    __syncthreads();
    int add = 0;
    for (int i = 0; i < (t >> 6); ++i) add += ws[i];
    v += add;
    int p = v - s;
    if (b0 + 0 <= nB2) bucketBase[b0 + 0] = p; p += c0;
    if (b0 + 1 <= nB2) bucketBase[b0 + 1] = p; p += c1;
    if (b0 + 2 <= nB2) bucketBase[b0 + 2] = p; p += c2;
    if (b0 + 3 <= nB2) bucketBase[b0 + 3] = p;
    if (t == 255) offsets[nodes] = v;  // grand total == nE
}

__global__ __launch_bounds__(256) void scatter2_kernel(const int* __restrict__ row,
                                                       const int* __restrict__ col,
                                                       const float* __restrict__ val,
                                                       const int* __restrict__ blockCounts,
                                                       const int* __restrict__ bucketBase,
                                                       int2* __restrict__ tmp,
                                                       int nB2, int nE, int chunk) {
    __shared__ int cur[MAXNB];
    int t = threadIdx.x;
    for (int b = t; b < nB2; b += 256)
        cur[b] = bucketBase[b] + blockCounts[blockIdx.x * nB2 + b];
    __syncthreads();
    int s0 = blockIdx.x * chunk;
    int s1 = s0 + chunk;
    if (s1 > nE) s1 = nE;
    for (int j = s0 + t; j < s1; j += 256) {
        int r = row[j];
        int p = atomicAdd(&cur[r >> 7], 1);  // LDS atomic
        int2 e;
        e.x = col[j] | ((r & 127) << 20);
        e.y = __float_as_int(val[j]);
        tmp[p] = e;
    }
}

// Pass 3: one block per 128-row bucket; LDS histogram + 2-wave scan -> row
// offsets, then re-scatter into final CSR order (dest = bucket's ~32KB window).
__global__ __launch_bounds__(256) void bucket_sort2_kernel(const int* __restrict__ bucketBase,
                                                           const int2* __restrict__ tmp,
                                                           int2* __restrict__ edges,
                                                           int* __restrict__ offsets,
                                                           int nodes) {
    __shared__ int rcnt[128];
    __shared__ int rcur[128];
    __shared__ int w0sum;
    int b = blockIdx.x;
    int t = threadIdx.x;
    int base = bucketBase[b];
    int cntE = bucketBase[b + 1] - base;
    if (t < 128) rcnt[t] = 0;
    __syncthreads();
    for (int j = t; j < cntE; j += 256) atomicAdd(&rcnt[tmp[base + j].x >> 20], 1);
    __syncthreads();
    int s = 0, v = 0;
    if (t < 128) {
        s = rcnt[t];
        v = s;
        int lane = t & 63;
#pragma unroll
        for (int d = 1; d < 64; d <<= 1) {
            int u = __shfl_up(v, d);
            if (lane >= d) v += u;
        }
        if (t == 63) w0sum = v;
    }
    __syncthreads();
    if (t < 128) {
        int excl = v - s + ((t >= 64) ? w0sum : 0);
        rcur[t] = base + excl;
        int r = (b << 7) + t;
        if (r < nodes) offsets[r] = base + excl;
    }
    __syncthreads();
    for (int j = t; j < cntE; j += 256) {
        int2 e = tmp[base + j];
        int pos = atomicAdd(&rcur[e.x >> 20], 1);  // LDS atomic
        int2 o;
        o.x = e.x & 0xFFFFF;
        o.y = e.y;
        edges[pos] = o;
    }
}

// ================= weight prep: fold BN, split fp32 -> bf16 hi/lo, transpose =================
__global__ void fold_split_kernel(const float* __restrict__ W, const float* __restrict__ b,
                                  const float* __restrict__ gamma, const float* __restrict__ beta,
                                  const float* __restrict__ mean, const float* __restrict__ var,
                                  unsigned short* __restrict__ WhT, unsigned short* __restrict__ WlT,
                                  float* __restrict__ bf, int K, int N) {
    int i = blockIdx.x * blockDim.x + threadIdx.x;
    if (i < K * N) {
        int k = i / N, n = i % N;
        float sc = gamma[n] * rsqrtf(var[n] + BN_EPS);
        float wf = W[i] * sc;
        unsigned short h = f2bf(wf);
        WhT[(size_t)n * K + k] = h;
        WlT[(size_t)n * K + k] = f2bf(wf - bf2f(h));
    }
    if (i < N) {
        float sc = gamma[i] * rsqrtf(var[i] + BN_EPS);
        bf[i] = (b[i] - mean[i]) * sc + beta[i];
    }
}

// W3 [K][40] -> padded transposed split [64][K]
__global__ void w3_split_kernel(const float* __restrict__ W3, unsigned short* __restrict__ WhT,
                                unsigned short* __restrict__ WlT, int K) {
    int i = blockIdx.x * blockDim.x + threadIdx.x;  // over 64*K
    if (i < 64 * K) {
        int n = i / K, k = i % K;
        float w = (n < 40) ? W3[k * 40 + n] : 0.0f;
        unsigned short h = f2bf(w);
        WhT[i] = h;
        WlT[i] = f2bf(w - bf2f(h));
    }
}

// fp32 -> bf16 elementwise (for the constant input x)
__global__ void cvt_bf16_kernel(const float* __restrict__ in, unsigned short* __restrict__ out,
                                int n) {
    int i = (blockIdx.x * blockDim.x + threadIdx.x) * 4;
    if (i < n) {
        f32x4 v = *reinterpret_cast<const f32x4*>(in + i);
        u16x4 o;
#pragma unroll
        for (int j = 0; j < 4; ++j) o[j] = f2bf(v[j]);
        *reinterpret_cast<u16x4*>(out + i) = o;
    }
}

// ================= SpMM over bf16 source (wave per row, fp32 accum, unroll-8) =================
template <int VW>
__global__ void spmm_bf16_kernel(const int* __restrict__ offsets, const int2* __restrict__ edges,
                                 const unsigned short* __restrict__ x,
                                 unsigned short* __restrict__ out,
                                 int sstride, int ostride, int nRows) {
    typedef float fvec __attribute__((ext_vector_type(VW)));
    int wave = threadIdx.x >> 6;
    int lane = threadIdx.x & 63;
    int r = blockIdx.x * 4 + wave;
    if (r >= nRows) return;
    int start = offsets[r], end = offsets[r + 1];
    fvec acc[4] = {};
    const unsigned short* xb = x + lane * VW;
    int j = start;
    for (; j + 7 < end; j += 8) {
        int2 e[8];
#pragma unroll
        for (int q = 0; q < 8; ++q) e[q] = edges[j + q];
        if constexpr (VW == 2) {
            unsigned u[8];
#pragma unroll
            for (int q = 0; q < 8; ++q)
                u[q] = *reinterpret_cast<const unsigned*>(xb + (size_t)e[q].x * sstride);
#pragma unroll
            for (int q = 0; q < 8; ++q) {
                float v = __int_as_float(e[q].y);
                acc[q & 3].x += v * __uint_as_float(u[q] << 16);
                acc[q & 3].y += v * __uint_as_float(u[q] & 0xFFFF0000u);
            }
        } else {
            uint2 u[8];
#pragma unroll
            for (int q = 0; q < 8; ++q)
                u[q] = *reinterpret_cast<const uint2*>(xb + (size_t)e[q].x * sstride);
#pragma unroll
            for (int q = 0; q < 8; ++q) {
                float v = __int_as_float(e[q].y);
                acc[q & 3][0] += v * __uint_as_float(u[q].x << 16);
                acc[q & 3][1] += v * __uint_as_float(u[q].x & 0xFFFF0000u);
                acc[q & 3][2] += v * __uint_as_float(u[q].y << 16);
                acc[q & 3][3] += v * __uint_as_float(u[q].y & 0xFFFF0000u);
            }
        }
    }
    for (; j < end; ++j) {
        int2 e = edges[j];
        float v = __int_as_float(e.y);
        if constexpr (VW == 2) {
            unsigned u = *reinterpret_cast<const unsigned*>(xb + (size_t)e.x * sstride);
            acc[0].x += v * __uint_as_float(u << 16);
            acc[0].y += v * __uint_as_float(u & 0xFFFF0000u);
        } else {
            uint2 u = *reinterpret_cast<const uint2*>(xb + (size_t)e.x * sstride);
            acc[0][0] += v * __uint_as_float(u.x << 16);
            acc[0][1] += v * __uint_as_float(u.x & 0xFFFF0000u);
            acc[0][2] += v * __uint_as_float(u.y << 16);
            acc[0][3] += v * __uint_as_float(u.y & 0xFFFF0000u);
        }
    }
    fvec res = (acc[0] + acc[1]) + (acc[2] + acc[3]);
    if constexpr (VW == 2) {
        unsigned o = (unsigned)f2bf(res.x) | ((unsigned)f2bf(res.y) << 16);
        __builtin_nontemporal_store(o,
            reinterpret_cast<unsigned*>(out + (size_t)r * ostride + lane * 2));
    } else {
        u16x4 o;
#pragma unroll
        for (int q = 0; q < 4; ++q) o[q] = f2bf(res[q]);
        __builtin_nontemporal_store(o,
            reinterpret_cast<u16x4*>(out + (size_t)r * ostride + lane * 4));
    }
}

// ================= SpMM over fp8-e4m3 source (z1), 256 cols, bf16 out =================
// Each lane: one u32 load = 4 fp8 features; HW cvt_pk decode; fp32 accum.
__global__ void spmm_fp8_kernel(const int* __restrict__ offsets, const int2* __restrict__ edges,
                                const unsigned char* __restrict__ x,
                                unsigned short* __restrict__ out, int nRows) {
    int wave = threadIdx.x >> 6;
    int lane = threadIdx.x & 63;
    int r = blockIdx.x * 4 + wave;
    if (r >= nRows) return;
    int start = offsets[r], end = offsets[r + 1];
    f32x4 acc[4] = {};
    const unsigned char* xb = x + lane * 4;
    int j = start;
    for (; j + 7 < end; j += 8) {
        int2 e[8];
#pragma unroll
        for (int q = 0; q < 8; ++q) e[q] = edges[j + q];
        unsigned u[8];
#pragma unroll
        for (int q = 0; q < 8; ++q)
            u[q] = *reinterpret_cast<const unsigned*>(xb + (size_t)e[q].x * 256);
#pragma unroll
        for (int q = 0; q < 8; ++q) {
            float v = __int_as_float(e[q].y);
            f32x2 lo = __builtin_amdgcn_cvt_pk_f32_fp8(u[q], false);
            f32x2 hi = __builtin_amdgcn_cvt_pk_f32_fp8(u[q], true);
            acc[q & 3][0] += v * lo.x;
            acc[q & 3][1] += v * lo.y;
            acc[q & 3][2] += v * hi.x;
            acc[q & 3][3] += v * hi.y;
        }
    }
    for (; j < end; ++j) {
        int2 e = edges[j];
        float v = __int_as_float(e.y);
        unsigned u = *reinterpret_cast<const unsigned*>(xb + (size_t)e.x * 256);
        f32x2 lo = __builtin_amdgcn_cvt_pk_f32_fp8(u, false);
        f32x2 hi = __builtin_amdgcn_cvt_pk_f32_fp8(u, true);
        acc[0][0] += v * lo.x;
        acc[0][1] += v * lo.y;
        acc[0][2] += v * hi.x;
        acc[0][3] += v * hi.y;
    }
    f32x4 res = (acc[0] + acc[1]) + (acc[2] + acc[3]);
    u16x4 o;
#pragma unroll
    for (int q = 0; q < 4; ++q) o[q] = f2bf(res[q]);
    __builtin_nontemporal_store(o, reinterpret_cast<u16x4*>(out + (size_t)r * 256 + lane * 4));
}

// SpMM over bf16 y [nodes][64] + bias + log_softmax over first 40 lanes; NT final store
__global__ void spmm3_lsm_kernel(const int* __restrict__ offsets, const int2* __restrict__ edges,
                                 const unsigned short* __restrict__ y, const float* __restrict__ b3,
                                 float* __restrict__ out, int nRows) {
    int wave = threadIdx.x >> 6;
    int lane = threadIdx.x & 63;
    int r = blockIdx.x * 4 + wave;
    if (r >= nRows) return;
    int start = offsets[r], end = offsets[r + 1];
    float a0 = 0.f, a1 = 0.f, a2 = 0.f, a3 = 0.f;
    const unsigned short* yb = y + lane;
    int j = start;
    for (; j + 7 < end; j += 8) {
        int2 e0 = edges[j], e1 = edges[j + 1], e2 = edges[j + 2], e3 = edges[j + 3];
        int2 e4 = edges[j + 4], e5 = edges[j + 5], e6 = edges[j + 6], e7 = edges[j + 7];
        float y0 = bf2f(yb[(size_t)e0.x * 64]);
        float y1 = bf2f(yb[(size_t)e1.x * 64]);
        float y2 = bf2f(yb[(size_t)e2.x * 64]);
        float y3 = bf2f(yb[(size_t)e3.x * 64]);
        float y4 = bf2f(yb[(size_t)e4.x * 64]);
        float y5 = bf2f(yb[(size_t)e5.x * 64]);
        float y6 = bf2f(yb[(size_t)e6.x * 64]);
        float y7 = bf2f(yb[(size_t)e7.x * 64]);
        a0 += __int_as_float(e0.y) * y0;
        a1 += __int_as_float(e1.y) * y1;
        a2 += __int_as_float(e2.y) * y2;
        a3 += __int_as_float(e3.y) * y3;
        a0 += __int_as_float(e4.y) * y4;
        a1 += __int_as_float(e5.y) * y5;
        a2 += __int_as_float(e6.y) * y6;
        a3 += __int_as_float(e7.y) * y7;
    }
    for (; j < end; ++j) {
        int2 e = edges[j];
        a0 += __int_as_float(e.y) * bf2f(yb[(size_t)e.x * 64]);
    }
    float acc = (a0 + a1) + (a2 + a3);
    float val = (lane < 40) ? (acc + b3[lane]) : -INFINITY;
    float m = val;
    for (int s = 32; s >= 1; s >>= 1) m = fmaxf(m, __shfl_xor(m, s));
    float e = (lane < 40) ? expf(val - m) : 0.f;
    float sum = e;
    for (int s = 32; s >= 1; s >>= 1) sum += __shfl_xor(sum, s);
    if (lane < 40)
        __builtin_nontemporal_store(val - m - logf(sum), out + (size_t)r * 40 + lane);
}

// ================= MFMA GEMM (A bf16, W bf16x2 split; LDS-staged 128xBN tile) =================
// OUTM: 0 = fp32, 1 = bf16, 2 = fp8 e4m3 (clamped +-448).
template <int K, int BN, int WM, int WN, bool RELU, bool HASBIAS, int OUTM>
__global__ __launch_bounds__(256) void gemm_a16_kernel(const unsigned short* __restrict__ A,
                                                       const unsigned short* __restrict__ BhT,
                                                       const unsigned short* __restrict__ BlT,
                                                       const float* __restrict__ bias,
                                                       void* __restrict__ Cv, int Cstride,
                                                       int nodes) {
    constexpr int BM = 128;
    constexpr int KS = 40;
    constexpr int NFM = BM / WM / 16;
    constexpr int NFN = BN / WN / 16;
    constexpr int ASL = BM * 4 / 256;  // = 2
    constexpr int BSL = BN * 4 / 256;  // 2 (BN=128) or 1 (BN=64)
    __shared__ unsigned short As[BM * KS];
    __shared__ unsigned short Bs_h[BN * KS], Bs_l[BN * KS];
    int t = threadIdx.x;
    int w = t >> 6, lane = t & 63;
    int wm = w % WM, wn = w / WM;
    int m0 = blockIdx.x * BM;
    int n0 = blockIdx.y * BN;
    int fr = lane & 15, fg = lane >> 4;
    f32x4 acc[NFM][NFN];
#pragma unroll
    for (int i = 0; i < NFM; ++i)
#pragma unroll
        for (int j = 0; j < NFN; ++j) acc[i][j] = f32x4{0.f, 0.f, 0.f, 0.f};

    for (int k0 = 0; k0 < K; k0 += 32) {
        bf16x8 ar[ASL];
#pragma unroll
        for (int s = 0; s < ASL; ++s) {
            int slot = t + s * 256;
            int row = slot >> 2, kb = slot & 3;
            ar[s] = *reinterpret_cast<const bf16x8*>(&A[(size_t)(m0 + row) * K + k0 + kb * 8]);
        }
        bf16x8 bhr[BSL], blr[BSL];
#pragma unroll
        for (int s = 0; s < BSL; ++s) {
            int slot = t + s * 256;
            int col = slot >> 2, kb = slot & 3;
            size_t off = (size_t)(n0 + col) * K + k0 + kb * 8;
            bhr[s] = *reinterpret_cast<const bf16x8*>(&BhT[off]);
            blr[s] = *reinterpret_cast<const bf16x8*>(&BlT[off]);
        }
        __syncthreads();  // prev-iter LDS reads done
#pragma unroll
        for (int s = 0; s < ASL; ++s) {
            int slot = t + s * 256;
            int row = slot >> 2, kb = slot & 3;
            *reinterpret_cast<bf16x8*>(&As[row * KS + kb * 8]) = ar[s];
        }
#pragma unroll
        for (int s = 0; s < BSL; ++s) {
            int slot = t + s * 256;
            int col = slot >> 2, kb = slot & 3;
            *reinterpret_cast<bf16x8*>(&Bs_h[col * KS + kb * 8]) = bhr[s];
            *reinterpret_cast<bf16x8*>(&Bs_l[col * KS + kb * 8]) = blr[s];
        }
        __syncthreads();  // LDS ready
        bf16x8 af[NFM];
#pragma unroll
        for (int fm = 0; fm < NFM; ++fm) {
            int arow = wm * (BM / WM) + fm * 16 + fr;
            af[fm] = *reinterpret_cast<bf16x8*>(&As[arow * KS + fg * 8]);
        }
#pragma unroll
        for (int fn = 0; fn < NFN; ++fn) {
            int bc = wn * (BN / WN) + fn * 16 + fr;
            bf16x8 bh = *reinterpret_cast<bf16x8*>(&Bs_h[bc * KS + fg * 8]);
            bf16x8 bl = *reinterpret_cast<bf16x8*>(&Bs_l[bc * KS + fg * 8]);
#pragma unroll
            for (int fm = 0; fm < NFM; ++fm) {
                acc[fm][fn] = __builtin_amdgcn_mfma_f32_16x16x32_bf16(af[fm], bh, acc[fm][fn], 0, 0, 0);
                acc[fm][fn] = __builtin_amdgcn_mfma_f32_16x16x32_bf16(af[fm], bl, acc[fm][fn], 0, 0, 0);
            }
        }
    }
    // epilogue: C/D mapping col = lane&15, row = (lane>>4)*4 + reg
#pragma unroll
    for (int fm = 0; fm < NFM; ++fm) {
#pragma unroll
        for (int fn = 0; fn < NFN; ++fn) {
            int col = n0 + wn * (BN / WN) + fn * 16 + fr;
            float bv = HASBIAS ? bias[col] : 0.f;
#pragma unroll
            for (int g = 0; g < 4; ++g) {
                int r = m0 + wm * (BM / WM) + fm * 16 + fg * 4 + g;
                if (r < nodes) {
                    float v = acc[fm][fn][g] + bv;
                    if (RELU) v = fmaxf(v, 0.f);
                    if (OUTM == 2) {
                        float c = fminf(fmaxf(v, -448.f), 448.f);
                        unsigned pk = __builtin_amdgcn_cvt_pk_fp8_f32(c, c, 0, false);
                        ((unsigned char*)Cv)[(size_t)r * Cstride + col] = (unsigned char)(pk & 0xFF);
                    } else if (OUTM == 1) {
                        ((unsigned short*)Cv)[(size_t)r * Cstride + col] = f2bf(v);
                    } else {
                        ((float*)Cv)[(size_t)r * Cstride + col] = v;
                    }
                }
            }
        }
    }
}

// ================= launch =================
extern "C" void kernel_launch(void* const* d_in, const int* in_sizes, int n_in,
                              void* d_out, int out_size, void* d_ws, size_t ws_size,
                              hipStream_t stream) {
    const float* x = (const float*)d_in[0];
    const int* erow = (const int*)d_in[1];
    const int* ecol = (const int*)d_in[2];
    const float* evals = (const float*)d_in[3];
    const float* W1 = (const float*)d_in[4];
    const float* b1 = (const float*)d_in[5];
    const float* W2 = (const float*)d_in[6];
    const float* b2 = (const float*)d_in[7];
    const float* W3 = (const float*)d_in[8];
    const float* b3 = (const float*)d_in[9];
    const float* gamma1 = (const float*)d_in[10];
    const float* beta1 = (const float*)d_in[11];
    const float* mean1 = (const float*)d_in[12];
    const float* var1 = (const float*)d_in[13];
    const float* gamma2 = (const float*)d_in[14];
    const float* beta2 = (const float*)d_in[15];
    const float* mean2 = (const float*)d_in[16];
    const float* var2 = (const float*)d_in[17];
    float* out = (float*)d_out;

    int nodes = in_sizes[0] / 128;
    int nE = in_sizes[1];
    int padRows = (nodes + 127) & ~127;  // 128-multiple for the GEMM tile
    int nB2 = (nodes + 127) >> 7;        // coarse buckets of 128 rows

    char* p = (char*)d_ws;
    auto carve = [&](size_t bytes) {
        void* r = (void*)p;
        p += (bytes + 255) & ~(size_t)255;
        return r;
    };
    int* offsets = (int*)carve((size_t)(nodes + 1) * 4);
    int* blockCounts = (int*)carve((size_t)B1 * nB2 * 4);
    int* bucketTotal = (int*)carve((size_t)nB2 * 4);
    int* bucketBase = (int*)carve((size_t)(nB2 + 1) * 4);
    int2* edges = (int2*)carve((size_t)nE * 8);
    unsigned short* WhT1 = (unsigned short*)carve(256 * 128 * 2);
    unsigned short* WlT1 = (unsigned short*)carve(256 * 128 * 2);
    unsigned short* WhT2 = (unsigned short*)carve(256 * 256 * 2);
    unsigned short* WlT2 = (unsigned short*)carve(256 * 256 * 2);
    unsigned short* WhT3 = (unsigned short*)carve(64 * 256 * 2);
    unsigned short* WlT3 = (unsigned short*)carve(64 * 256 * 2);
    float* b1f = (float*)carve(256 * 4);
    float* b2f = (float*)carve(256 * 4);
    float* bufA = (float*)carve((size_t)padRows * 256 * 4);
    float* bufB = (float*)carve((size_t)padRows * 256 * 4);
    // aliases (sequential lifetimes):
    int2* tmp = (int2*)bufA;                        // CSR staging; dead before spmm1 writes h16
    unsigned short* xb16 = (unsigned short*)bufB;   // x bf16 [nodes][128]; dead after spmm1
    unsigned short* h16 = (unsigned short*)bufA;    // h bf16 [padRows][128]; dead after gemm1
    unsigned char* z1f8 = (unsigned char*)bufB;     // z1 fp8 [nodes][256]; dead after spmm2
    unsigned short* h2b16 = (unsigned short*)bufA;  // h2 bf16 [padRows][256]; dead after gemm2
    unsigned short* z2b16 = (unsigned short*)bufB;  // z2 bf16 [padRows][256]; dead after gemm3
    unsigned short* y16 = (unsigned short*)bufA;    // y bf16 [padRows][64]; after h2 dies

    // ---- CSR build: count -> scan -> scatter -> per-bucket sort (no global atomics) ----
    int chunk = (nE + B1 - 1) / B1;
    count_kernel<<<B1, 256, 0, stream>>>(erow, blockCounts, nB2, nE, chunk);
    scan_buckets_kernel<<<nB2, 256, 0, stream>>>(blockCounts, bucketTotal, nB2);
    scan_total_kernel<<<1, 256, 0, stream>>>(bucketTotal, bucketBase, offsets, nB2, nodes);
    scatter2_kernel<<<B1, 256, 0, stream>>>(erow, ecol, evals, blockCounts, bucketBase, tmp, nB2,
                                            nE, chunk);
    bucket_sort2_kernel<<<nB2, 256, 0, stream>>>(bucketBase, tmp, edges, offsets, nodes);

    // ---- weight prep: fold BN + bf16 hi/lo split + transpose ----
    fold_split_kernel<<<(128 * 256 + 255) / 256, 256, 0, stream>>>(
        W1, b1, gamma1, beta1, mean1, var1, WhT1, WlT1, b1f, 128, 256);
    fold_split_kernel<<<(256 * 256 + 255) / 256, 256, 0, stream>>>(
        W2, b2, gamma2, beta2, mean2, var2, WhT2, WlT2, b2f, 256, 256);
    w3_split_kernel<<<(64 * 256 + 255) / 256, 256, 0, stream>>>(W3, WhT3, WlT3, 256);

    // ---- pipeline ----
    int gR = (nodes + 3) / 4;
    int gM = padRows / 128;

    // x -> bf16 (gather source for layer 1)
    int nX = nodes * 128;
    cvt_bf16_kernel<<<(nX / 4 + 255) / 256, 256, 0, stream>>>(x, xb16, nX);
    // layer 1: h(bf16) = A*x_bf16 ; z1(fp8) = relu(h @ W1' + b1')
    spmm_bf16_kernel<2><<<gR, 256, 0, stream>>>(offsets, edges, xb16, h16, 128, 128, nodes);
    gemm_a16_kernel<128, 128, 2, 2, true, true, 2><<<dim3(gM, 2), 256, 0, stream>>>(
        h16, WhT1, WlT1, b1f, z1f8, 256, nodes);
    // layer 2: h2(bf16) = A*z1_fp8 (single 256-col pass); z2(bf16) = relu(h2 @ W2' + b2')
    spmm_fp8_kernel<<<gR, 256, 0, stream>>>(offsets, edges, z1f8, h2b16, nodes);
    gemm_a16_kernel<256, 128, 2, 2, true, true, 1><<<dim3(gM, 2), 256, 0, stream>>>(
        h2b16, WhT2, WlT2, b2f, z2b16, 256, nodes);
    // layer 3 (reassociated): y(bf16) = z2 @ W3 (padded 64 cols); out = logsoftmax(A*y + b3)
    gemm_a16_kernel<256, 64, 4, 1, false, false, 1><<<dim3(gM, 1), 256, 0, stream>>>(
        z2b16, WhT3, WlT3, nullptr, y16, 64, nodes);
    spmm3_lsm_kernel<<<gR, 256, 0, stream>>>(offsets, edges, y16, b3, out, nodes);
}

// Round 19
// 521.493 us; speedup vs baseline: 1.5076x; 1.0677x over previous
//
#include <hip/hip_runtime.h>
#include <hip/hip_bf16.h>
#include <math.h>

#define BN_EPS 1e-5f
#define B1 256      // edge-chunk blocks for count/scatter passes (must == blockDim)
#define MAXNB 1024  // max coarse buckets (128 rows each); 100k nodes -> 782

typedef float f32x4 __attribute__((ext_vector_type(4)));
typedef float f32x2 __attribute__((ext_vector_type(2)));
typedef short bf16x8 __attribute__((ext_vector_type(8)));
typedef unsigned short u16x4 __attribute__((ext_vector_type(4)));

__device__ inline unsigned short f2bf(float v) {
    unsigned b = __float_as_uint(v);
    unsigned r = (b + 0x7FFFu + ((b >> 16) & 1u)) >> 16;
    return (unsigned short)r;
}
__device__ inline float bf2f(unsigned short h) {
    return __uint_as_float(((unsigned)h) << 16);
}

// ================= CSR build (atomic-free at global scope) =================
__global__ __launch_bounds__(256) void count_kernel(const int* __restrict__ row,
                                                    int* __restrict__ blockCounts,
                                                    int nB2, int nE, int chunk) {
    __shared__ int hist[MAXNB];
    int t = threadIdx.x;
    for (int b = t; b < nB2; b += 256) hist[b] = 0;
    __syncthreads();
    int s0 = blockIdx.x * chunk;
    int s1 = s0 + chunk;
    if (s1 > nE) s1 = nE;
    for (int j = s0 + t; j < s1; j += 256) atomicAdd(&hist[row[j] >> 7], 1);
    __syncthreads();
    for (int b = t; b < nB2; b += 256) blockCounts[blockIdx.x * nB2 + b] = hist[b];
}

__global__ __launch_bounds__(256) void scan_buckets_kernel(int* __restrict__ blockCounts,
                                                           int* __restrict__ bucketTotal,
                                                           int nB2) {
    int b = blockIdx.x;
    int t = threadIdx.x;
    int lane = t & 63;
    int s = blockCounts[t * nB2 + b];
    int v = s;
#pragma unroll
    for (int d = 1; d < 64; d <<= 1) {
        int u = __shfl_up(v, d);
        if (lane >= d) v += u;
    }
    __shared__ int ws[4];
    if (lane == 63) ws[t >> 6] = v;
    __syncthreads();
    int add = 0;
    for (int i = 0; i < (t >> 6); ++i) add += ws[i];
    v += add;
    blockCounts[t * nB2 + b] = v - s;  // exclusive within bucket
    if (t == 255) bucketTotal[b] = v;
}

__global__ __launch_bounds__(256) void scan_total_kernel(const int* __restrict__ bucketTotal,
                                                         int* __restrict__ bucketBase,
                                                         int* __restrict__ offsets,
                                                         int nB2, int nodes) {
    int t = threadIdx.x;
    int lane = t & 63;
    int b0 = t * 4;
    int c0 = (b0 + 0 < nB2) ? bucketTotal[b0 + 0] : 0;
    int c1 = (b0 + 1 < nB2) ? bucketTotal[b0 + 1] : 0;
    int c2 = (b0 + 2 < nB2) ? bucketTotal[b0 + 2] : 0;
    int c3 = (b0 + 3 < nB2) ? bucketTotal[b0 + 3] : 0;
    int s = c0 + c1 + c2 + c3;
    int v = s;
#pragma unroll
    for (int d = 1; d < 64; d <<= 1) {
        int u = __shfl_up(v, d);
        if (lane >= d) v += u;
    }
    __shared__ int ws[4];
    if (lane == 63) ws[t >> 6] = v;
    __syncthreads();
    int add = 0;
    for (int i = 0; i < (t >> 6); ++i) add += ws[i];
    v += add;
    int p = v - s;
    if (b0 + 0 <= nB2) bucketBase[b0 + 0] = p; p += c0;
    if (b0 + 1 <= nB2) bucketBase[b0 + 1] = p; p += c1;
    if (b0 + 2 <= nB2) bucketBase[b0 + 2] = p; p += c2;
    if (b0 + 3 <= nB2) bucketBase[b0 + 3] = p;
    if (t == 255) offsets[nodes] = v;  // grand total == nE
}

__global__ __launch_bounds__(256) void scatter2_kernel(const int* __restrict__ row,
                                                       const int* __restrict__ col,
                                                       const float* __restrict__ val,
                                                       const int* __restrict__ blockCounts,
                                                       const int* __restrict__ bucketBase,
                                                       int2* __restrict__ tmp,
                                                       int nB2, int nE, int chunk) {
    __shared__ int cur[MAXNB];
    int t = threadIdx.x;
    for (int b = t; b < nB2; b += 256)
        cur[b] = bucketBase[b] + blockCounts[blockIdx.x * nB2 + b];
    __syncthreads();
    int s0 = blockIdx.x * chunk;
    int s1 = s0 + chunk;
    if (s1 > nE) s1 = nE;
    for (int j = s0 + t; j < s1; j += 256) {
        int r = row[j];
        int p = atomicAdd(&cur[r >> 7], 1);  // LDS atomic
        int2 e;
        e.x = col[j] | ((r & 127) << 20);
        e.y = __float_as_int(val[j]);
        tmp[p] = e;
    }
}

// Pass 3: one block per 128-row bucket; LDS histogram + 2-wave scan -> row
// offsets, then re-scatter into final CSR order (dest = bucket's ~32KB window).
__global__ __launch_bounds__(256) void bucket_sort2_kernel(const int* __restrict__ bucketBase,
                                                           const int2* __restrict__ tmp,
                                                           int2* __restrict__ edges,
                                                           int* __restrict__ offsets,
                                                           int nodes) {
    __shared__ int rcnt[128];
    __shared__ int rcur[128];
    __shared__ int w0sum;
    int b = blockIdx.x;
    int t = threadIdx.x;
    int base = bucketBase[b];
    int cntE = bucketBase[b + 1] - base;
    if (t < 128) rcnt[t] = 0;
    __syncthreads();
    for (int j = t; j < cntE; j += 256) atomicAdd(&rcnt[tmp[base + j].x >> 20], 1);
    __syncthreads();
    int s = 0, v = 0;
    if (t < 128) {
        s = rcnt[t];
        v = s;
        int lane = t & 63;
#pragma unroll
        for (int d = 1; d < 64; d <<= 1) {
            int u = __shfl_up(v, d);
            if (lane >= d) v += u;
        }
        if (t == 63) w0sum = v;
    }
    __syncthreads();
    if (t < 128) {
        int excl = v - s + ((t >= 64) ? w0sum : 0);
        rcur[t] = base + excl;
        int r = (b << 7) + t;
        if (r < nodes) offsets[r] = base + excl;
    }
    __syncthreads();
    for (int j = t; j < cntE; j += 256) {
        int2 e = tmp[base + j];
        int pos = atomicAdd(&rcur[e.x >> 20], 1);  // LDS atomic
        int2 o;
        o.x = e.x & 0xFFFFF;
        o.y = e.y;
        edges[pos] = o;
    }
}

// ================= weight prep: fold BN, split fp32 -> bf16 hi/lo, transpose =================
__global__ void fold_split_kernel(const float* __restrict__ W, const float* __restrict__ b,
                                  const float* __restrict__ gamma, const float* __restrict__ beta,
                                  const float* __restrict__ mean, const float* __restrict__ var,
                                  unsigned short* __restrict__ WhT, unsigned short* __restrict__ WlT,
                                  float* __restrict__ bf, int K, int N) {
    int i = blockIdx.x * blockDim.x + threadIdx.x;
    if (i < K * N) {
        int k = i / N, n = i % N;
        float sc = gamma[n] * rsqrtf(var[n] + BN_EPS);
        float wf = W[i] * sc;
        unsigned short h = f2bf(wf);
        WhT[(size_t)n * K + k] = h;
        WlT[(size_t)n * K + k] = f2bf(wf - bf2f(h));
    }
    if (i < N) {
        float sc = gamma[i] * rsqrtf(var[i] + BN_EPS);
        bf[i] = (b[i] - mean[i]) * sc + beta[i];
    }
}

// W3 [K][40] -> padded transposed split [64][K]
__global__ void w3_split_kernel(const float* __restrict__ W3, unsigned short* __restrict__ WhT,
                                unsigned short* __restrict__ WlT, int K) {
    int i = blockIdx.x * blockDim.x + threadIdx.x;  // over 64*K
    if (i < 64 * K) {
        int n = i / K, k = i % K;
        float w = (n < 40) ? W3[k * 40 + n] : 0.0f;
        unsigned short h = f2bf(w);
        WhT[i] = h;
        WlT[i] = f2bf(w - bf2f(h));
    }
}

// fp32 -> fp8 e4m3 elementwise (for the constant input x; |x| << 448, no clamp)
__global__ void cvt_fp8_kernel(const float* __restrict__ in, unsigned* __restrict__ out, int n4) {
    int i = blockIdx.x * blockDim.x + threadIdx.x;  // over n/4
    if (i < n4) {
        f32x4 v = *reinterpret_cast<const f32x4*>(in + i * 4);
        unsigned pk = __builtin_amdgcn_cvt_pk_fp8_f32(v[0], v[1], 0, false);
        pk = __builtin_amdgcn_cvt_pk_fp8_f32(v[2], v[3], pk, true);
        out[i] = pk;
    }
}

// ================= SpMM over fp8-e4m3 source (wave/row, fp32 accum, unroll-8, bf16 out) ====
// VW fp8 features per lane (2 or 4); sstride/ostride in elements.
template <int VW>
__global__ void spmm_fp8_kernel(const int* __restrict__ offsets, const int2* __restrict__ edges,
                                const unsigned char* __restrict__ x,
                                unsigned short* __restrict__ out,
                                int sstride, int ostride, int nRows) {
    int wave = threadIdx.x >> 6;
    int lane = threadIdx.x & 63;
    int r = blockIdx.x * 4 + wave;
    if (r >= nRows) return;
    int start = offsets[r], end = offsets[r + 1];
    typedef float fvec __attribute__((ext_vector_type(VW)));
    fvec acc[4] = {};
    const unsigned char* xb = x + lane * VW;
    int j = start;
    for (; j + 7 < end; j += 8) {
        int2 e[8];
#pragma unroll
        for (int q = 0; q < 8; ++q) e[q] = edges[j + q];
        unsigned u[8];
#pragma unroll
        for (int q = 0; q < 8; ++q) {
            if constexpr (VW == 4)
                u[q] = *reinterpret_cast<const unsigned*>(xb + (size_t)e[q].x * sstride);
            else
                u[q] = *reinterpret_cast<const unsigned short*>(xb + (size_t)e[q].x * sstride);
        }
#pragma unroll
        for (int q = 0; q < 8; ++q) {
            float v = __int_as_float(e[q].y);
            f32x2 lo = __builtin_amdgcn_cvt_pk_f32_fp8(u[q], false);
            acc[q & 3][0] += v * lo.x;
            acc[q & 3][1] += v * lo.y;
            if constexpr (VW == 4) {
                f32x2 hi = __builtin_amdgcn_cvt_pk_f32_fp8(u[q], true);
                acc[q & 3][2] += v * hi.x;
                acc[q & 3][3] += v * hi.y;
            }
        }
    }
    for (; j < end; ++j) {
        int2 e = edges[j];
        float v = __int_as_float(e.y);
        unsigned u;
        if constexpr (VW == 4)
            u = *reinterpret_cast<const unsigned*>(xb + (size_t)e.x * sstride);
        else
            u = *reinterpret_cast<const unsigned short*>(xb + (size_t)e.x * sstride);
        f32x2 lo = __builtin_amdgcn_cvt_pk_f32_fp8(u, false);
        acc[0][0] += v * lo.x;
        acc[0][1] += v * lo.y;
        if constexpr (VW == 4) {
            f32x2 hi = __builtin_amdgcn_cvt_pk_f32_fp8(u, true);
            acc[0][2] += v * hi.x;
            acc[0][3] += v * hi.y;
        }
    }
    fvec res = (acc[0] + acc[1]) + (acc[2] + acc[3]);
    if constexpr (VW == 2) {
        unsigned o = (unsigned)f2bf(res[0]) | ((unsigned)f2bf(res[1]) << 16);
        __builtin_nontemporal_store(o,
            reinterpret_cast<unsigned*>(out + (size_t)r * ostride + lane * 2));
    } else {
        u16x4 o;
#pragma unroll
        for (int q = 0; q < 4; ++q) o[q] = f2bf(res[q]);
        __builtin_nontemporal_store(o,
            reinterpret_cast<u16x4*>(out + (size_t)r * ostride + lane * 4));
    }
}

// SpMM over fp8 y [nodes][64] + bias + log_softmax over first 40 lanes; NT final store
__global__ void spmm3_lsm_kernel(const int* __restrict__ offsets, const int2* __restrict__ edges,
                                 const unsigned char* __restrict__ y, const float* __restrict__ b3,
                                 float* __restrict__ out, int nRows) {
    int wave = threadIdx.x >> 6;
    int lane = threadIdx.x & 63;
    int r = blockIdx.x * 4 + wave;
    if (r >= nRows) return;
    int start = offsets[r], end = offsets[r + 1];
    float a0 = 0.f, a1 = 0.f, a2 = 0.f, a3 = 0.f;
    const unsigned char* yb = y + lane;
    int j = start;
    for (; j + 7 < end; j += 8) {
        int2 e[8];
#pragma unroll
        for (int q = 0; q < 8; ++q) e[q] = edges[j + q];
        unsigned u[8];
#pragma unroll
        for (int q = 0; q < 8; ++q) u[q] = yb[(size_t)e[q].x * 64];
#pragma unroll
        for (int q = 0; q < 8; ++q) {
            float yv = __builtin_amdgcn_cvt_f32_fp8(u[q], 0);
            float v = __int_as_float(e[q].y);
            if ((q & 3) == 0) a0 += v * yv;
            else if ((q & 3) == 1) a1 += v * yv;
            else if ((q & 3) == 2) a2 += v * yv;
            else a3 += v * yv;
        }
    }
    for (; j < end; ++j) {
        int2 e = edges[j];
        float yv = __builtin_amdgcn_cvt_f32_fp8((unsigned)yb[(size_t)e.x * 64], 0);
        a0 += __int_as_float(e.y) * yv;
    }
    float acc = (a0 + a1) + (a2 + a3);
    float val = (lane < 40) ? (acc + b3[lane]) : -INFINITY;
    float m = val;
    for (int s = 32; s >= 1; s >>= 1) m = fmaxf(m, __shfl_xor(m, s));
    float e = (lane < 40) ? expf(val - m) : 0.f;
    float sum = e;
    for (int s = 32; s >= 1; s >>= 1) sum += __shfl_xor(sum, s);
    if (lane < 40)
        __builtin_nontemporal_store(val - m - logf(sum), out + (size_t)r * 40 + lane);
}

// ================= MFMA GEMM (A bf16, W bf16x2 split; LDS-staged 128xBN tile) =================
// OUTM: 0 = fp32, 1 = bf16, 2 = fp8 e4m3 (clamped +-448).
template <int K, int BN, int WM, int WN, bool RELU, bool HASBIAS, int OUTM>
__global__ __launch_bounds__(256) void gemm_a16_kernel(const unsigned short* __restrict__ A,
                                                       const unsigned short* __restrict__ BhT,
                                                       const unsigned short* __restrict__ BlT,
                                                       const float* __restrict__ bias,
                                                       void* __restrict__ Cv, int Cstride,
                                                       int nodes) {
    constexpr int BM = 128;
    constexpr int KS = 40;
    constexpr int NFM = BM / WM / 16;
    constexpr int NFN = BN / WN / 16;
    constexpr int ASL = BM * 4 / 256;  // = 2
    constexpr int BSL = BN * 4 / 256;  // 2 (BN=128) or 1 (BN=64)
    __shared__ unsigned short As[BM * KS];
    __shared__ unsigned short Bs_h[BN * KS], Bs_l[BN * KS];
    int t = threadIdx.x;
    int w = t >> 6, lane = t & 63;
    int wm = w % WM, wn = w / WM;
    int m0 = blockIdx.x * BM;
    int n0 = blockIdx.y * BN;
    int fr = lane & 15, fg = lane >> 4;
    f32x4 acc[NFM][NFN];
#pragma unroll
    for (int i = 0; i < NFM; ++i)
#pragma unroll
        for (int j = 0; j < NFN; ++j) acc[i][j] = f32x4{0.f, 0.f, 0.f, 0.f};

    for (int k0 = 0; k0 < K; k0 += 32) {
        bf16x8 ar[ASL];
#pragma unroll
        for (int s = 0; s < ASL; ++s) {
            int slot = t + s * 256;
            int row = slot >> 2, kb = slot & 3;
            ar[s] = *reinterpret_cast<const bf16x8*>(&A[(size_t)(m0 + row) * K + k0 + kb * 8]);
        }
        bf16x8 bhr[BSL], blr[BSL];
#pragma unroll
        for (int s = 0; s < BSL; ++s) {
            int slot = t + s * 256;
            int col = slot >> 2, kb = slot & 3;
            size_t off = (size_t)(n0 + col) * K + k0 + kb * 8;
            bhr[s] = *reinterpret_cast<const bf16x8*>(&BhT[off]);
            blr[s] = *reinterpret_cast<const bf16x8*>(&BlT[off]);
        }
        __syncthreads();  // prev-iter LDS reads done
#pragma unroll
        for (int s = 0; s < ASL; ++s) {
            int slot = t + s * 256;
            int row = slot >> 2, kb = slot & 3;
            *reinterpret_cast<bf16x8*>(&As[row * KS + kb * 8]) = ar[s];
        }
#pragma unroll
        for (int s = 0; s < BSL; ++s) {
            int slot = t + s * 256;
            int col = slot >> 2, kb = slot & 3;
            *reinterpret_cast<bf16x8*>(&Bs_h[col * KS + kb * 8]) = bhr[s];
            *reinterpret_cast<bf16x8*>(&Bs_l[col * KS + kb * 8]) = blr[s];
        }
        __syncthreads();  // LDS ready
        bf16x8 af[NFM];
#pragma unroll
        for (int fm = 0; fm < NFM; ++fm) {
            int arow = wm * (BM / WM) + fm * 16 + fr;
            af[fm] = *reinterpret_cast<bf16x8*>(&As[arow * KS + fg * 8]);
        }
#pragma unroll
        for (int fn = 0; fn < NFN; ++fn) {
            int bc = wn * (BN / WN) + fn * 16 + fr;
            bf16x8 bh = *reinterpret_cast<bf16x8*>(&Bs_h[bc * KS + fg * 8]);
            bf16x8 bl = *reinterpret_cast<bf16x8*>(&Bs_l[bc * KS + fg * 8]);
#pragma unroll
            for (int fm = 0; fm < NFM; ++fm) {
                acc[fm][fn] = __builtin_amdgcn_mfma_f32_16x16x32_bf16(af[fm], bh, acc[fm][fn], 0, 0, 0);
                acc[fm][fn] = __builtin_amdgcn_mfma_f32_16x16x32_bf16(af[fm], bl, acc[fm][fn], 0, 0, 0);
            }
        }
    }
    // epilogue: C/D mapping col = lane&15, row = (lane>>4)*4 + reg
#pragma unroll
    for (int fm = 0; fm < NFM; ++fm) {
#pragma unroll
        for (int fn = 0; fn < NFN; ++fn) {
            int col = n0 + wn * (BN / WN) + fn * 16 + fr;
            float bv = HASBIAS ? bias[col] : 0.f;
#pragma unroll
            for (int g = 0; g < 4; ++g) {
                int r = m0 + wm * (BM / WM) + fm * 16 + fg * 4 + g;
                if (r < nodes) {
                    float v = acc[fm][fn][g] + bv;
                    if (RELU) v = fmaxf(v, 0.f);
                    if (OUTM == 2) {
                        float c = fminf(fmaxf(v, -448.f), 448.f);
                        unsigned pk = __builtin_amdgcn_cvt_pk_fp8_f32(c, c, 0, false);
                        ((unsigned char*)Cv)[(size_t)r * Cstride + col] = (unsigned char)(pk & 0xFF);
                    } else if (OUTM == 1) {
                        ((unsigned short*)Cv)[(size_t)r * Cstride + col] = f2bf(v);
                    } else {
                        ((float*)Cv)[(size_t)r * Cstride + col] = v;
                    }
                }
            }
        }
    }
}

// ================= launch =================
extern "C" void kernel_launch(void* const* d_in, const int* in_sizes, int n_in,
                              void* d_out, int out_size, void* d_ws, size_t ws_size,
                              hipStream_t stream) {
    const float* x = (const float*)d_in[0];
    const int* erow = (const int*)d_in[1];
    const int* ecol = (const int*)d_in[2];
    const float* evals = (const float*)d_in[3];
    const float* W1 = (const float*)d_in[4];
    const float* b1 = (const float*)d_in[5];
    const float* W2 = (const float*)d_in[6];
    const float* b2 = (const float*)d_in[7];
    const float* W3 = (const float*)d_in[8];
    const float* b3 = (const float*)d_in[9];
    const float* gamma1 = (const float*)d_in[10];
    const float* beta1 = (const float*)d_in[11];
    const float* mean1 = (const float*)d_in[12];
    const float* var1 = (const float*)d_in[13];
    const float* gamma2 = (const float*)d_in[14];
    const float* beta2 = (const float*)d_in[15];
    const float* mean2 = (const float*)d_in[16];
    const float* var2 = (const float*)d_in[17];
    float* out = (float*)d_out;

    int nodes = in_sizes[0] / 128;
    int nE = in_sizes[1];
    int padRows = (nodes + 127) & ~127;  // 128-multiple for the GEMM tile
    int nB2 = (nodes + 127) >> 7;        // coarse buckets of 128 rows

    char* p = (char*)d_ws;
    auto carve = [&](size_t bytes) {
        void* r = (void*)p;
        p += (bytes + 255) & ~(size_t)255;
        return r;
    };
    int* offsets = (int*)carve((size_t)(nodes + 1) * 4);
    int* blockCounts = (int*)carve((size_t)B1 * nB2 * 4);
    int* bucketTotal = (int*)carve((size_t)nB2 * 4);
    int* bucketBase = (int*)carve((size_t)(nB2 + 1) * 4);
    int2* edges = (int2*)carve((size_t)nE * 8);
    unsigned short* WhT1 = (unsigned short*)carve(256 * 128 * 2);
    unsigned short* WlT1 = (unsigned short*)carve(256 * 128 * 2);
    unsigned short* WhT2 = (unsigned short*)carve(256 * 256 * 2);
    unsigned short* WlT2 = (unsigned short*)carve(256 * 256 * 2);
    unsigned short* WhT3 = (unsigned short*)carve(64 * 256 * 2);
    unsigned short* WlT3 = (unsigned short*)carve(64 * 256 * 2);
    float* b1f = (float*)carve(256 * 4);
    float* b2f = (float*)carve(256 * 4);
    float* bufA = (float*)carve((size_t)padRows * 256 * 4);
    float* bufB = (float*)carve((size_t)padRows * 256 * 4);
    // aliases (sequential lifetimes):
    int2* tmp = (int2*)bufA;                        // CSR staging; dead before spmm1 writes h16
    unsigned char* xf8 = (unsigned char*)bufB;      // x fp8 [nodes][128]; dead after spmm1
    unsigned short* h16 = (unsigned short*)bufA;    // h bf16 [padRows][128]; dead after gemm1
    unsigned char* z1f8 = (unsigned char*)bufB;     // z1 fp8 [nodes][256]; dead after spmm2
    unsigned short* h2b16 = (unsigned short*)bufA;  // h2 bf16 [padRows][256]; dead after gemm2
    unsigned short* z2b16 = (unsigned short*)bufB;  // z2 bf16 [padRows][256]; dead after gemm3
    unsigned char* yf8 = (unsigned char*)bufA;      // y fp8 [padRows][64]; after h2 dies

    // ---- CSR build: count -> scan -> scatter -> per-bucket sort (no global atomics) ----
    int chunk = (nE + B1 - 1) / B1;
    count_kernel<<<B1, 256, 0, stream>>>(erow, blockCounts, nB2, nE, chunk);
    scan_buckets_kernel<<<nB2, 256, 0, stream>>>(blockCounts, bucketTotal, nB2);
    scan_total_kernel<<<1, 256, 0, stream>>>(bucketTotal, bucketBase, offsets, nB2, nodes);
    scatter2_kernel<<<B1, 256, 0, stream>>>(erow, ecol, evals, blockCounts, bucketBase, tmp, nB2,
                                            nE, chunk);
    bucket_sort2_kernel<<<nB2, 256, 0, stream>>>(bucketBase, tmp, edges, offsets, nodes);

    // ---- weight prep: fold BN + bf16 hi/lo split + transpose ----
    fold_split_kernel<<<(128 * 256 + 255) / 256, 256, 0, stream>>>(
        W1, b1, gamma1, beta1, mean1, var1, WhT1, WlT1, b1f, 128, 256);
    fold_split_kernel<<<(256 * 256 + 255) / 256, 256, 0, stream>>>(
        W2, b2, gamma2, beta2, mean2, var2, WhT2, WlT2, b2f, 256, 256);
    w3_split_kernel<<<(64 * 256 + 255) / 256, 256, 0, stream>>>(W3, WhT3, WlT3, 256);

    // ---- pipeline ----
    int gR = (nodes + 3) / 4;
    int gM = padRows / 128;

    // x -> fp8 (gather source for layer 1; N(0,1) values, e4m3-safe)
    int nX4 = nodes * 128 / 4;
    cvt_fp8_kernel<<<(nX4 + 255) / 256, 256, 0, stream>>>(x, (unsigned*)xf8, nX4);
    // layer 1: h(bf16) = A*x_fp8 ; z1(fp8) = relu(h @ W1' + b1')
    spmm_fp8_kernel<2><<<gR, 256, 0, stream>>>(offsets, edges, xf8, h16, 128, 128, nodes);
    gemm_a16_kernel<128, 128, 2, 2, true, true, 2><<<dim3(gM, 2), 256, 0, stream>>>(
        h16, WhT1, WlT1, b1f, z1f8, 256, nodes);
    // layer 2: h2(bf16) = A*z1_fp8 (single 256-col pass); z2(bf16) = relu(h2 @ W2' + b2')
    spmm_fp8_kernel<4><<<gR, 256, 0, stream>>>(offsets, edges, z1f8, h2b16, 256, 256, nodes);
    gemm_a16_kernel<256, 128, 2, 2, true, true, 1><<<dim3(gM, 2), 256, 0, stream>>>(
        h2b16, WhT2, WlT2, b2f, z2b16, 256, nodes);
    // layer 3 (reassociated): y(fp8) = z2 @ W3 (padded 64 cols); out = logsoftmax(A*y + b3)
    gemm_a16_kernel<256, 64, 4, 1, false, false, 2><<<dim3(gM, 1), 256, 0, stream>>>(
        z2b16, WhT3, WlT3, nullptr, yf8, 64, nodes);
    spmm3_lsm_kernel<<<gR, 256, 0, stream>>>(offsets, edges, yf8, b3, out, nodes);
}

// Round 20
// 485.989 us; speedup vs baseline: 1.6178x; 1.0731x over previous
//
#include <hip/hip_runtime.h>
#include <hip/hip_bf16.h>
#include <math.h>

#define BN_EPS 1e-5f
#define B1 256      // edge-chunk blocks for count/scatter passes (must == blockDim)
#define MAXNB 1024  // max coarse buckets (128 rows each); 100k nodes -> 782

typedef float f32x4 __attribute__((ext_vector_type(4)));
typedef float f32x2 __attribute__((ext_vector_type(2)));
typedef short bf16x8 __attribute__((ext_vector_type(8)));
typedef unsigned short u16x4 __attribute__((ext_vector_type(4)));

__device__ inline unsigned short f2bf(float v) {
    unsigned b = __float_as_uint(v);
    unsigned r = (b + 0x7FFFu + ((b >> 16) & 1u)) >> 16;
    return (unsigned short)r;
}
__device__ inline float bf2f(unsigned short h) {
    return __uint_as_float(((unsigned)h) << 16);
}
// packed edge: col in [16:0] (nodes < 2^17), val = positive bf16 sans sign in [31:17]
__device__ inline float edge_val(unsigned w) {
    return __uint_as_float((w >> 17) << 16);
}

// ================= CSR build (atomic-free at global scope) =================
__global__ __launch_bounds__(256) void count_kernel(const int* __restrict__ row,
                                                    int* __restrict__ blockCounts,
                                                    int nB2, int nE, int chunk) {
    __shared__ int hist[MAXNB];
    int t = threadIdx.x;
    for (int b = t; b < nB2; b += 256) hist[b] = 0;
    __syncthreads();
    int s0 = blockIdx.x * chunk;
    int s1 = s0 + chunk;
    if (s1 > nE) s1 = nE;
    for (int j = s0 + t; j < s1; j += 256) atomicAdd(&hist[row[j] >> 7], 1);
    __syncthreads();
    for (int b = t; b < nB2; b += 256) blockCounts[blockIdx.x * nB2 + b] = hist[b];
}

__global__ __launch_bounds__(256) void scan_buckets_kernel(int* __restrict__ blockCounts,
                                                           int* __restrict__ bucketTotal,
                                                           int nB2) {
    int b = blockIdx.x;
    int t = threadIdx.x;
    int lane = t & 63;
    int s = blockCounts[t * nB2 + b];
    int v = s;
#pragma unroll
    for (int d = 1; d < 64; d <<= 1) {
        int u = __shfl_up(v, d);
        if (lane >= d) v += u;
    }
    __shared__ int ws[4];
    if (lane == 63) ws[t >> 6] = v;
    __syncthreads();
    int add = 0;
    for (int i = 0; i < (t >> 6); ++i) add += ws[i];
    v += add;
    blockCounts[t * nB2 + b] = v - s;  // exclusive within bucket
    if (t == 255) bucketTotal[b] = v;
}

__global__ __launch_bounds__(256) void scan_total_kernel(const int* __restrict__ bucketTotal,
                                                         int* __restrict__ bucketBase,
                                                         int* __restrict__ offsets,
                                                         int nB2, int nodes) {
    int t = threadIdx.x;
    int lane = t & 63;
    int b0 = t * 4;
    int c0 = (b0 + 0 < nB2) ? bucketTotal[b0 + 0] : 0;
    int c1 = (b0 + 1 < nB2) ? bucketTotal[b0 + 1] : 0;
    int c2 = (b0 + 2 < nB2) ? bucketTotal[b0 + 2] : 0;
    int c3 = (b0 + 3 < nB2) ? bucketTotal[b0 + 3] : 0;
    int s = c0 + c1 + c2 + c3;
    int v = s;
#pragma unroll
    for (int d = 1; d < 64; d <<= 1) {
        int u = __shfl_up(v, d);
        if (lane >= d) v += u;
    }
    __shared__ int ws[4];
    if (lane == 63) ws[t >> 6] = v;
    __syncthreads();
    int add = 0;
    for (int i = 0; i < (t >> 6); ++i) add += ws[i];
    v += add;
    int p = v - s;
    if (b0 + 0 <= nB2) bucketBase[b0 + 0] = p; p += c0;
    if (b0 + 1 <= nB2) bucketBase[b0 + 1] = p; p += c1;
    if (b0 + 2 <= nB2) bucketBase[b0 + 2] = p; p += c2;
    if (b0 + 3 <= nB2) bucketBase[b0 + 3] = p;
    if (t == 255) offsets[nodes] = v;  // grand total == nE
}

__global__ __launch_bounds__(256) void scatter2_kernel(const int* __restrict__ row,
                                                       const int* __restrict__ col,
                                                       const float* __restrict__ val,
                                                       const int* __restrict__ blockCounts,
                                                       const int* __restrict__ bucketBase,
                                                       int2* __restrict__ tmp,
                                                       int nB2, int nE, int chunk) {
    __shared__ int cur[MAXNB];
    int t = threadIdx.x;
    for (int b = t; b < nB2; b += 256)
        cur[b] = bucketBase[b] + blockCounts[blockIdx.x * nB2 + b];
    __syncthreads();
    int s0 = blockIdx.x * chunk;
    int s1 = s0 + chunk;
    if (s1 > nE) s1 = nE;
    for (int j = s0 + t; j < s1; j += 256) {
        int r = row[j];
        int p = atomicAdd(&cur[r >> 7], 1);  // LDS atomic
        int2 e;
        e.x = col[j] | ((r & 127) << 20);
        e.y = __float_as_int(val[j]);
        tmp[p] = e;
    }
}

// Pass 3: one block per 128-row bucket; LDS histogram + 2-wave scan -> row
// offsets, then re-scatter into final CSR order. Packs {col, val-bf15} in 4B.
__global__ __launch_bounds__(256) void bucket_sort2_kernel(const int* __restrict__ bucketBase,
                                                           const int2* __restrict__ tmp,
                                                           unsigned* __restrict__ edges,
                                                           int* __restrict__ offsets,
                                                           int nodes) {
    __shared__ int rcnt[128];
    __shared__ int rcur[128];
    __shared__ int w0sum;
    int b = blockIdx.x;
    int t = threadIdx.x;
    int base = bucketBase[b];
    int cntE = bucketBase[b + 1] - base;
    if (t < 128) rcnt[t] = 0;
    __syncthreads();
    for (int j = t; j < cntE; j += 256) atomicAdd(&rcnt[tmp[base + j].x >> 20], 1);
    __syncthreads();
    int s = 0, v = 0;
    if (t < 128) {
        s = rcnt[t];
        v = s;
        int lane = t & 63;
#pragma unroll
        for (int d = 1; d < 64; d <<= 1) {
            int u = __shfl_up(v, d);
            if (lane >= d) v += u;
        }
        if (t == 63) w0sum = v;
    }
    __syncthreads();
    if (t < 128) {
        int excl = v - s + ((t >= 64) ? w0sum : 0);
        rcur[t] = base + excl;
        int r = (b << 7) + t;
        if (r < nodes) offsets[r] = base + excl;
    }
    __syncthreads();
    for (int j = t; j < cntE; j += 256) {
        int2 e = tmp[base + j];
        int pos = atomicAdd(&rcur[e.x >> 20], 1);  // LDS atomic
        unsigned vb = (unsigned)f2bf(__int_as_float(e.y)) & 0x7FFFu;
        edges[pos] = (unsigned)(e.x & 0x1FFFF) | (vb << 17);
    }
}

// ================= weight prep: fold BN into W (bf16), transpose [N][K] ==========
__global__ void fold_kernel(const float* __restrict__ W, const float* __restrict__ b,
                            const float* __restrict__ gamma, const float* __restrict__ beta,
                            const float* __restrict__ mean, const float* __restrict__ var,
                            unsigned short* __restrict__ WhT, float* __restrict__ bf,
                            int K, int N) {
    int i = blockIdx.x * blockDim.x + threadIdx.x;
    if (i < K * N) {
        int k = i / N, n = i % N;
        float sc = gamma[n] * rsqrtf(var[n] + BN_EPS);
        WhT[(size_t)n * K + k] = f2bf(W[i] * sc);
    }
    if (i < N) {
        float sc = gamma[i] * rsqrtf(var[i] + BN_EPS);
        bf[i] = (b[i] - mean[i]) * sc + beta[i];
    }
}

// W3 [K][40] -> padded transposed bf16 [64][K]
__global__ void w3_kernel(const float* __restrict__ W3, unsigned short* __restrict__ WhT, int K) {
    int i = blockIdx.x * blockDim.x + threadIdx.x;  // over 64*K
    if (i < 64 * K) {
        int n = i / K, k = i % K;
        WhT[i] = f2bf((n < 40) ? W3[k * 40 + n] : 0.0f);
    }
}

// fp32 -> fp8 e4m3 elementwise (for the constant input x; |x| << 448, no clamp)
__global__ void cvt_fp8_kernel(const float* __restrict__ in, unsigned* __restrict__ out, int n4) {
    int i = blockIdx.x * blockDim.x + threadIdx.x;  // over n/4
    if (i < n4) {
        f32x4 v = *reinterpret_cast<const f32x4*>(in + i * 4);
        unsigned pk = __builtin_amdgcn_cvt_pk_fp8_f32(v[0], v[1], 0, false);
        pk = __builtin_amdgcn_cvt_pk_fp8_f32(v[2], v[3], pk, true);
        out[i] = pk;
    }
}

// ================= SpMM over fp8-e4m3 source (wave/row, fp32 accum, unroll-8, bf16 out) ====
// VW fp8 features per lane (2 or 4); sstride/ostride in elements. 4B packed edges.
template <int VW>
__global__ void spmm_fp8_kernel(const int* __restrict__ offsets, const unsigned* __restrict__ edges,
                                const unsigned char* __restrict__ x,
                                unsigned short* __restrict__ out,
                                int sstride, int ostride, int nRows) {
    int wave = threadIdx.x >> 6;
    int lane = threadIdx.x & 63;
    int r = blockIdx.x * 4 + wave;
    if (r >= nRows) return;
    int start = offsets[r], end = offsets[r + 1];
    typedef float fvec __attribute__((ext_vector_type(VW)));
    fvec acc[4] = {};
    const unsigned char* xb = x + lane * VW;
    int j = start;
    for (; j + 7 < end; j += 8) {
        unsigned w[8];
#pragma unroll
        for (int q = 0; q < 8; ++q) w[q] = edges[j + q];
        unsigned u[8];
#pragma unroll
        for (int q = 0; q < 8; ++q) {
            size_t c = (size_t)(w[q] & 0x1FFFF) * sstride;
            if constexpr (VW == 4)
                u[q] = *reinterpret_cast<const unsigned*>(xb + c);
            else
                u[q] = *reinterpret_cast<const unsigned short*>(xb + c);
        }
#pragma unroll
        for (int q = 0; q < 8; ++q) {
            float v = edge_val(w[q]);
            f32x2 lo = __builtin_amdgcn_cvt_pk_f32_fp8(u[q], false);
            acc[q & 3][0] += v * lo.x;
            acc[q & 3][1] += v * lo.y;
            if constexpr (VW == 4) {
                f32x2 hi = __builtin_amdgcn_cvt_pk_f32_fp8(u[q], true);
                acc[q & 3][2] += v * hi.x;
                acc[q & 3][3] += v * hi.y;
            }
        }
    }
    for (; j < end; ++j) {
        unsigned w = edges[j];
        float v = edge_val(w);
        size_t c = (size_t)(w & 0x1FFFF) * sstride;
        unsigned u;
        if constexpr (VW == 4)
            u = *reinterpret_cast<const unsigned*>(xb + c);
        else
            u = *reinterpret_cast<const unsigned short*>(xb + c);
        f32x2 lo = __builtin_amdgcn_cvt_pk_f32_fp8(u, false);
        acc[0][0] += v * lo.x;
        acc[0][1] += v * lo.y;
        if constexpr (VW == 4) {
            f32x2 hi = __builtin_amdgcn_cvt_pk_f32_fp8(u, true);
            acc[0][2] += v * hi.x;
            acc[0][3] += v * hi.y;
        }
    }
    fvec res = (acc[0] + acc[1]) + (acc[2] + acc[3]);
    if constexpr (VW == 2) {
        unsigned o = (unsigned)f2bf(res[0]) | ((unsigned)f2bf(res[1]) << 16);
        __builtin_nontemporal_store(o,
            reinterpret_cast<unsigned*>(out + (size_t)r * ostride + lane * 2));
    } else {
        u16x4 o;
#pragma unroll
        for (int q = 0; q < 4; ++q) o[q] = f2bf(res[q]);
        __builtin_nontemporal_store(o,
            reinterpret_cast<u16x4*>(out + (size_t)r * ostride + lane * 4));
    }
}

// SpMM over fp8 y [nodes][64] + bias + log_softmax over first 40 lanes; NT final store
__global__ void spmm3_lsm_kernel(const int* __restrict__ offsets, const unsigned* __restrict__ edges,
                                 const unsigned char* __restrict__ y, const float* __restrict__ b3,
                                 float* __restrict__ out, int nRows) {
    int wave = threadIdx.x >> 6;
    int lane = threadIdx.x & 63;
    int r = blockIdx.x * 4 + wave;
    if (r >= nRows) return;
    int start = offsets[r], end = offsets[r + 1];
    float a0 = 0.f, a1 = 0.f, a2 = 0.f, a3 = 0.f;
    const unsigned char* yb = y + lane;
    int j = start;
    for (; j + 7 < end; j += 8) {
        unsigned w[8];
#pragma unroll
        for (int q = 0; q < 8; ++q) w[q] = edges[j + q];
        unsigned u[8];
#pragma unroll
        for (int q = 0; q < 8; ++q) u[q] = yb[(size_t)(w[q] & 0x1FFFF) * 64];
#pragma unroll
        for (int q = 0; q < 8; ++q) {
            float yv = __builtin_amdgcn_cvt_f32_fp8(u[q], 0);
            float v = edge_val(w[q]);
            if ((q & 3) == 0) a0 += v * yv;
            else if ((q & 3) == 1) a1 += v * yv;
            else if ((q & 3) == 2) a2 += v * yv;
            else a3 += v * yv;
        }
    }
    for (; j < end; ++j) {
        unsigned w = edges[j];
        float yv = __builtin_amdgcn_cvt_f32_fp8((unsigned)yb[(size_t)(w & 0x1FFFF) * 64], 0);
        a0 += edge_val(w) * yv;
    }
    float acc = (a0 + a1) + (a2 + a3);
    float val = (lane < 40) ? (acc + b3[lane]) : -INFINITY;
    float m = val;
    for (int s = 32; s >= 1; s >>= 1) m = fmaxf(m, __shfl_xor(m, s));
    float e = (lane < 40) ? expf(val - m) : 0.f;
    float sum = e;
    for (int s = 32; s >= 1; s >>= 1) sum += __shfl_xor(sum, s);
    if (lane < 40)
        __builtin_nontemporal_store(val - m - logf(sum), out + (size_t)r * 40 + lane);
}

// ================= MFMA GEMM (A bf16, W bf16; LDS-staged 128xBN tile) =================
// OUTM: 0 = fp32, 1 = bf16, 2 = fp8 e4m3 (clamped +-448).
template <int K, int BN, int WM, int WN, bool RELU, bool HASBIAS, int OUTM>
__global__ __launch_bounds__(256) void gemm_a16_kernel(const unsigned short* __restrict__ A,
                                                       const unsigned short* __restrict__ BhT,
                                                       const float* __restrict__ bias,
                                                       void* __restrict__ Cv, int Cstride,
                                                       int nodes) {
    constexpr int BM = 128;
    constexpr int KS = 40;
    constexpr int NFM = BM / WM / 16;
    constexpr int NFN = BN / WN / 16;
    constexpr int ASL = BM * 4 / 256;  // = 2
    constexpr int BSL = BN * 4 / 256;  // 2 (BN=128) or 1 (BN=64)
    __shared__ unsigned short As[BM * KS];
    __shared__ unsigned short Bs[BN * KS];
    int t = threadIdx.x;
    int w = t >> 6, lane = t & 63;
    int wm = w % WM, wn = w / WM;
    int m0 = blockIdx.x * BM;
    int n0 = blockIdx.y * BN;
    int fr = lane & 15, fg = lane >> 4;
    f32x4 acc[NFM][NFN];
#pragma unroll
    for (int i = 0; i < NFM; ++i)
#pragma unroll
        for (int j = 0; j < NFN; ++j) acc[i][j] = f32x4{0.f, 0.f, 0.f, 0.f};

    for (int k0 = 0; k0 < K; k0 += 32) {
        bf16x8 ar[ASL];
#pragma unroll
        for (int s = 0; s < ASL; ++s) {
            int slot = t + s * 256;
            int row = slot >> 2, kb = slot & 3;
            ar[s] = *reinterpret_cast<const bf16x8*>(&A[(size_t)(m0 + row) * K + k0 + kb * 8]);
        }
        bf16x8 bhr[BSL];
#pragma unroll
        for (int s = 0; s < BSL; ++s) {
            int slot = t + s * 256;
            int col = slot >> 2, kb = slot & 3;
            bhr[s] = *reinterpret_cast<const bf16x8*>(&BhT[(size_t)(n0 + col) * K + k0 + kb * 8]);
        }
        __syncthreads();  // prev-iter LDS reads done
#pragma unroll
        for (int s = 0; s < ASL; ++s) {
            int slot = t + s * 256;
            int row = slot >> 2, kb = slot & 3;
            *reinterpret_cast<bf16x8*>(&As[row * KS + kb * 8]) = ar[s];
        }
#pragma unroll
        for (int s = 0; s < BSL; ++s) {
            int slot = t + s * 256;
            int col = slot >> 2, kb = slot & 3;
            *reinterpret_cast<bf16x8*>(&Bs[col * KS + kb * 8]) = bhr[s];
        }
        __syncthreads();  // LDS ready
        bf16x8 af[NFM];
#pragma unroll
        for (int fm = 0; fm < NFM; ++fm) {
            int arow = wm * (BM / WM) + fm * 16 + fr;
            af[fm] = *reinterpret_cast<bf16x8*>(&As[arow * KS + fg * 8]);
        }
#pragma unroll
        for (int fn = 0; fn < NFN; ++fn) {
            int bc = wn * (BN / WN) + fn * 16 + fr;
            bf16x8 bh = *reinterpret_cast<bf16x8*>(&Bs[bc * KS + fg * 8]);
#pragma unroll
            for (int fm = 0; fm < NFM; ++fm) {
                acc[fm][fn] = __builtin_amdgcn_mfma_f32_16x16x32_bf16(af[fm], bh, acc[fm][fn], 0, 0, 0);
            }
        }
    }
    // epilogue: C/D mapping col = lane&15, row = (lane>>4)*4 + reg
#pragma unroll
    for (int fm = 0; fm < NFM; ++fm) {
#pragma unroll
        for (int fn = 0; fn < NFN; ++fn) {
            int col = n0 + wn * (BN / WN) + fn * 16 + fr;
            float bv = HASBIAS ? bias[col] : 0.f;
#pragma unroll
            for (int g = 0; g < 4; ++g) {
                int r = m0 + wm * (BM / WM) + fm * 16 + fg * 4 + g;
                if (r < nodes) {
                    float v = acc[fm][fn][g] + bv;
                    if (RELU) v = fmaxf(v, 0.f);
                    if (OUTM == 2) {
                        float c = fminf(fmaxf(v, -448.f), 448.f);
                        unsigned pk = __builtin_amdgcn_cvt_pk_fp8_f32(c, c, 0, false);
                        ((unsigned char*)Cv)[(size_t)r * Cstride + col] = (unsigned char)(pk & 0xFF);
                    } else if (OUTM == 1) {
                        ((unsigned short*)Cv)[(size_t)r * Cstride + col] = f2bf(v);
                    } else {
                        ((float*)Cv)[(size_t)r * Cstride + col] = v;
                    }
                }
            }
        }
    }
}

// ================= launch =================
extern "C" void kernel_launch(void* const* d_in, const int* in_sizes, int n_in,
                              void* d_out, int out_size, void* d_ws, size_t ws_size,
                              hipStream_t stream) {
    const float* x = (const float*)d_in[0];
    const int* erow = (const int*)d_in[1];
    const int* ecol = (const int*)d_in[2];
    const float* evals = (const float*)d_in[3];
    const float* W1 = (const float*)d_in[4];
    const float* b1 = (const float*)d_in[5];
    const float* W2 = (const float*)d_in[6];
    const float* b2 = (const float*)d_in[7];
    const float* W3 = (const float*)d_in[8];
    const float* b3 = (const float*)d_in[9];
    const float* gamma1 = (const float*)d_in[10];
    const float* beta1 = (const float*)d_in[11];
    const float* mean1 = (const float*)d_in[12];
    const float* var1 = (const float*)d_in[13];
    const float* gamma2 = (const float*)d_in[14];
    const float* beta2 = (const float*)d_in[15];
    const float* mean2 = (const float*)d_in[16];
    const float* var2 = (const float*)d_in[17];
    float* out = (float*)d_out;

    int nodes = in_sizes[0] / 128;
    int nE = in_sizes[1];
    int padRows = (nodes + 127) & ~127;  // 128-multiple for the GEMM tile
    int nB2 = (nodes + 127) >> 7;        // coarse buckets of 128 rows

    char* p = (char*)d_ws;
    auto carve = [&](size_t bytes) {
        void* r = (void*)p;
        p += (bytes + 255) & ~(size_t)255;
        return r;
    };
    int* offsets = (int*)carve((size_t)(nodes + 1) * 4);
    int* blockCounts = (int*)carve((size_t)B1 * nB2 * 4);
    int* bucketTotal = (int*)carve((size_t)nB2 * 4);
    int* bucketBase = (int*)carve((size_t)(nB2 + 1) * 4);
    unsigned* edges = (unsigned*)carve((size_t)nE * 4);
    unsigned short* WhT1 = (unsigned short*)carve(256 * 128 * 2);
    unsigned short* WhT2 = (unsigned short*)carve(256 * 256 * 2);
    unsigned short* WhT3 = (unsigned short*)carve(64 * 256 * 2);
    float* b1f = (float*)carve(256 * 4);
    float* b2f = (float*)carve(256 * 4);
    float* bufA = (float*)carve((size_t)padRows * 256 * 4);
    float* bufB = (float*)carve((size_t)padRows * 256 * 4);
    // aliases (sequential lifetimes):
    int2* tmp = (int2*)bufA;                        // CSR staging; dead before spmm1 writes h16
    unsigned char* xf8 = (unsigned char*)bufB;      // x fp8 [nodes][128]; dead after spmm1
    unsigned short* h16 = (unsigned short*)bufA;    // h bf16 [padRows][128]; dead after gemm1
    unsigned char* z1f8 = (unsigned char*)bufB;     // z1 fp8 [nodes][256]; dead after spmm2
    unsigned short* h2b16 = (unsigned short*)bufA;  // h2 bf16 [padRows][256]; dead after gemm2
    unsigned short* z2b16 = (unsigned short*)bufB;  // z2 bf16 [padRows][256]; dead after gemm3
    unsigned char* yf8 = (unsigned char*)bufA;      // y fp8 [padRows][64]; after h2 dies

    // ---- CSR build: count -> scan -> scatter -> per-bucket sort (no global atomics) ----
    int chunk = (nE + B1 - 1) / B1;
    count_kernel<<<B1, 256, 0, stream>>>(erow, blockCounts, nB2, nE, chunk);
    scan_buckets_kernel<<<nB2, 256, 0, stream>>>(blockCounts, bucketTotal, nB2);
    scan_total_kernel<<<1, 256, 0, stream>>>(bucketTotal, bucketBase, offsets, nB2, nodes);
    scatter2_kernel<<<B1, 256, 0, stream>>>(erow, ecol, evals, blockCounts, bucketBase, tmp, nB2,
                                            nE, chunk);
    bucket_sort2_kernel<<<nB2, 256, 0, stream>>>(bucketBase, tmp, edges, offsets, nodes);

    // ---- weight prep: fold BN into bf16 W, transpose ----
    fold_kernel<<<(128 * 256 + 255) / 256, 256, 0, stream>>>(W1, b1, gamma1, beta1, mean1, var1,
                                                             WhT1, b1f, 128, 256);
    fold_kernel<<<(256 * 256 + 255) / 256, 256, 0, stream>>>(W2, b2, gamma2, beta2, mean2, var2,
                                                             WhT2, b2f, 256, 256);
    w3_kernel<<<(64 * 256 + 255) / 256, 256, 0, stream>>>(W3, WhT3, 256);

    // ---- pipeline ----
    int gR = (nodes + 3) / 4;
    int gM = padRows / 128;

    // x -> fp8 (gather source for layer 1; N(0,1) values, e4m3-safe)
    int nX4 = nodes * 128 / 4;
    cvt_fp8_kernel<<<(nX4 + 255) / 256, 256, 0, stream>>>(x, (unsigned*)xf8, nX4);
    // layer 1: h(bf16) = A*x_fp8 ; z1(fp8) = relu(h @ W1' + b1')
    spmm_fp8_kernel<2><<<gR, 256, 0, stream>>>(offsets, edges, xf8, h16, 128, 128, nodes);
    gemm_a16_kernel<128, 128, 2, 2, true, true, 2><<<dim3(gM, 2), 256, 0, stream>>>(
        h16, WhT1, b1f, z1f8, 256, nodes);
    // layer 2: h2(bf16) = A*z1_fp8 (single 256-col pass); z2(bf16) = relu(h2 @ W2' + b2')
    spmm_fp8_kernel<4><<<gR, 256, 0, stream>>>(offsets, edges, z1f8, h2b16, 256, 256, nodes);
    gemm_a16_kernel<256, 128, 2, 2, true, true, 1><<<dim3(gM, 2), 256, 0, stream>>>(
        h2b16, WhT2, b2f, z2b16, 256, nodes);
    // layer 3 (reassociated): y(fp8) = z2 @ W3 (padded 64 cols); out = logsoftmax(A*y + b3)
    gemm_a16_kernel<256, 64, 4, 1, false, false, 2><<<dim3(gM, 1), 256, 0, stream>>>(
        z2b16, WhT3, nullptr, yf8, 64, nodes);
    spmm3_lsm_kernel<<<gR, 256, 0, stream>>>(offsets, edges, yf8, b3, out, nodes);
}

// Round 21
// 475.793 us; speedup vs baseline: 1.6525x; 1.0214x over previous
//
#include <hip/hip_runtime.h>
#include <hip/hip_bf16.h>
#include <math.h>

#define BN_EPS 1e-5f
#define B1 256      // edge-chunk blocks for count/scatter passes (must == blockDim)
#define MAXNB 1024  // max coarse buckets (128 rows each); 100k nodes -> 782

typedef float f32x4 __attribute__((ext_vector_type(4)));
typedef float f32x2 __attribute__((ext_vector_type(2)));
typedef short bf16x8 __attribute__((ext_vector_type(8)));
typedef unsigned short u16x4 __attribute__((ext_vector_type(4)));

__device__ inline unsigned short f2bf(float v) {
    unsigned b = __float_as_uint(v);
    unsigned r = (b + 0x7FFFu + ((b >> 16) & 1u)) >> 16;
    return (unsigned short)r;
}
__device__ inline float bf2f(unsigned short h) {
    return __uint_as_float(((unsigned)h) << 16);
}
// packed edge: col in [16:0] (nodes < 2^17); val = positive float's top 15 bits in [31:17]
// (sign=0, 8-bit exp, 6-bit mantissa). Decode = single AND.
__device__ inline float edge_val(unsigned w) {
    return __uint_as_float(w & 0xFFFE0000u);
}
__device__ inline unsigned pack_val(float v) {
    unsigned b = __float_as_uint(v);
    // round-to-nearest-even at bit 17
    unsigned r = (b + 0xFFFFu + ((b >> 17) & 1u)) & 0xFFFE0000u;
    return r;
}

// ================= CSR build (atomic-free at global scope) =================
__global__ __launch_bounds__(256) void count_kernel(const int* __restrict__ row,
                                                    int* __restrict__ blockCounts,
                                                    int nB2, int nE, int chunk) {
    __shared__ int hist[MAXNB];
    int t = threadIdx.x;
    for (int b = t; b < nB2; b += 256) hist[b] = 0;
    __syncthreads();
    int s0 = blockIdx.x * chunk;
    int s1 = s0 + chunk;
    if (s1 > nE) s1 = nE;
    for (int j = s0 + t; j < s1; j += 256) atomicAdd(&hist[row[j] >> 7], 1);
    __syncthreads();
    for (int b = t; b < nB2; b += 256) blockCounts[blockIdx.x * nB2 + b] = hist[b];
}

__global__ __launch_bounds__(256) void scan_buckets_kernel(int* __restrict__ blockCounts,
                                                           int* __restrict__ bucketTotal,
                                                           int nB2) {
    int b = blockIdx.x;
    int t = threadIdx.x;
    int lane = t & 63;
    int s = blockCounts[t * nB2 + b];
    int v = s;
#pragma unroll
    for (int d = 1; d < 64; d <<= 1) {
        int u = __shfl_up(v, d);
        if (lane >= d) v += u;
    }
    __shared__ int ws[4];
    if (lane == 63) ws[t >> 6] = v;
    __syncthreads();
    int add = 0;
    for (int i = 0; i < (t >> 6); ++i) add += ws[i];
    v += add;
    blockCounts[t * nB2 + b] = v - s;  // exclusive within bucket
    if (t == 255) bucketTotal[b] = v;
}

__global__ __launch_bounds__(256) void scan_total_kernel(const int* __restrict__ bucketTotal,
                                                         int* __restrict__ bucketBase,
                                                         int* __restrict__ offsets,
                                                         int nB2, int nodes) {
    int t = threadIdx.x;
    int lane = t & 63;
    int b0 = t * 4;
    int c0 = (b0 + 0 < nB2) ? bucketTotal[b0 + 0] : 0;
    int c1 = (b0 + 1 < nB2) ? bucketTotal[b0 + 1] : 0;
    int c2 = (b0 + 2 < nB2) ? bucketTotal[b0 + 2] : 0;
    int c3 = (b0 + 3 < nB2) ? bucketTotal[b0 + 3] : 0;
    int s = c0 + c1 + c2 + c3;
    int v = s;
#pragma unroll
    for (int d = 1; d < 64; d <<= 1) {
        int u = __shfl_up(v, d);
        if (lane >= d) v += u;
    }
    __shared__ int ws[4];
    if (lane == 63) ws[t >> 6] = v;
    __syncthreads();
    int add = 0;
    for (int i = 0; i < (t >> 6); ++i) add += ws[i];
    v += add;
    int p = v - s;
    if (b0 + 0 <= nB2) bucketBase[b0 + 0] = p; p += c0;
    if (b0 + 1 <= nB2) bucketBase[b0 + 1] = p; p += c1;
    if (b0 + 2 <= nB2) bucketBase[b0 + 2] = p; p += c2;
    if (b0 + 3 <= nB2) bucketBase[b0 + 3] = p;
    if (t == 255) offsets[nodes] = v;  // grand total == nE
}

__global__ __launch_bounds__(256) void scatter2_kernel(const int* __restrict__ row,
                                                       const int* __restrict__ col,
                                                       const float* __restrict__ val,
                                                       const int* __restrict__ blockCounts,
                                                       const int* __restrict__ bucketBase,
                                                       int2* __restrict__ tmp,
                                                       int nB2, int nE, int chunk) {
    __shared__ int cur[MAXNB];
    int t = threadIdx.x;
    for (int b = t; b < nB2; b += 256)
        cur[b] = bucketBase[b] + blockCounts[blockIdx.x * nB2 + b];
    __syncthreads();
    int s0 = blockIdx.x * chunk;
    int s1 = s0 + chunk;
    if (s1 > nE) s1 = nE;
    for (int j = s0 + t; j < s1; j += 256) {
        int r = row[j];
        int p = atomicAdd(&cur[r >> 7], 1);  // LDS atomic
        int2 e;
        e.x = col[j] | ((r & 127) << 20);
        e.y = __float_as_int(val[j]);
        tmp[p] = e;
    }
}

// Pass 3: one block per 128-row bucket; LDS histogram + 2-wave scan -> row
// offsets, then re-scatter into final CSR order. Packs {col, val-f15} in 4B.
__global__ __launch_bounds__(256) void bucket_sort2_kernel(const int* __restrict__ bucketBase,
                                                           const int2* __restrict__ tmp,
                                                           unsigned* __restrict__ edges,
                                                           int* __restrict__ offsets,
                                                           int nodes) {
    __shared__ int rcnt[128];
    __shared__ int rcur[128];
    __shared__ int w0sum;
    int b = blockIdx.x;
    int t = threadIdx.x;
    int base = bucketBase[b];
    int cntE = bucketBase[b + 1] - base;
    if (t < 128) rcnt[t] = 0;
    __syncthreads();
    for (int j = t; j < cntE; j += 256) atomicAdd(&rcnt[tmp[base + j].x >> 20], 1);
    __syncthreads();
    int s = 0, v = 0;
    if (t < 128) {
        s = rcnt[t];
        v = s;
        int lane = t & 63;
#pragma unroll
        for (int d = 1; d < 64; d <<= 1) {
            int u = __shfl_up(v, d);
            if (lane >= d) v += u;
        }
        if (t == 63) w0sum = v;
    }
    __syncthreads();
    if (t < 128) {
        int excl = v - s + ((t >= 64) ? w0sum : 0);
        rcur[t] = base + excl;
        int r = (b << 7) + t;
        if (r < nodes) offsets[r] = base + excl;
    }
    __syncthreads();
    for (int j = t; j < cntE; j += 256) {
        int2 e = tmp[base + j];
        int pos = atomicAdd(&rcur[e.x >> 20], 1);  // LDS atomic
        edges[pos] = (unsigned)(e.x & 0x1FFFF) | pack_val(__int_as_float(e.y));
    }
}

// ================= weight prep: fold BN into W (bf16), transpose [N][K] ==========
__global__ void fold_kernel(const float* __restrict__ W, const float* __restrict__ b,
                            const float* __restrict__ gamma, const float* __restrict__ beta,
                            const float* __restrict__ mean, const float* __restrict__ var,
                            unsigned short* __restrict__ WhT, float* __restrict__ bf,
                            int K, int N) {
    int i = blockIdx.x * blockDim.x + threadIdx.x;
    if (i < K * N) {
        int k = i / N, n = i % N;
        float sc = gamma[n] * rsqrtf(var[n] + BN_EPS);
        WhT[(size_t)n * K + k] = f2bf(W[i] * sc);
    }
    if (i < N) {
        float sc = gamma[i] * rsqrtf(var[i] + BN_EPS);
        bf[i] = (b[i] - mean[i]) * sc + beta[i];
    }
}

// W3 [K][40] -> padded transposed bf16 [64][K]
__global__ void w3_kernel(const float* __restrict__ W3, unsigned short* __restrict__ WhT, int K) {
    int i = blockIdx.x * blockDim.x + threadIdx.x;  // over 64*K
    if (i < 64 * K) {
        int n = i / K, k = i % K;
        WhT[i] = f2bf((n < 40) ? W3[k * 40 + n] : 0.0f);
    }
}

// fp32 -> fp8 e4m3 elementwise (for the constant input x; |x| << 448, no clamp)
__global__ void cvt_fp8_kernel(const float* __restrict__ in, unsigned* __restrict__ out, int n4) {
    int i = blockIdx.x * blockDim.x + threadIdx.x;  // over n/4
    if (i < n4) {
        f32x4 v = *reinterpret_cast<const f32x4*>(in + i * 4);
        unsigned pk = __builtin_amdgcn_cvt_pk_fp8_f32(v[0], v[1], 0, false);
        pk = __builtin_amdgcn_cvt_pk_fp8_f32(v[2], v[3], pk, true);
        out[i] = pk;
    }
}

// ================= SpMM over fp8-e4m3 source (wave/row, fp32 accum, unroll-8, bf16 out) ====
// VW fp8 features per lane (2 or 4); SS/OS = source/output strides (compile-time).
template <int VW, int SS, int OS>
__global__ void spmm_fp8_kernel(const int* __restrict__ offsets, const unsigned* __restrict__ edges,
                                const unsigned char* __restrict__ x,
                                unsigned short* __restrict__ out, int nRows) {
    int wave = threadIdx.x >> 6;
    int lane = threadIdx.x & 63;
    int r = blockIdx.x * 4 + wave;
    if (r >= nRows) return;
    int start = offsets[r], end = offsets[r + 1];
    typedef float fvec __attribute__((ext_vector_type(VW)));
    fvec acc[4] = {};
    const unsigned char* xb = x + lane * VW;
    int j = start;
    for (; j + 7 < end; j += 8) {
        unsigned w[8];
#pragma unroll
        for (int q = 0; q < 8; ++q) w[q] = edges[j + q];
        unsigned u[8];
#pragma unroll
        for (int q = 0; q < 8; ++q) {
            size_t c = (size_t)(w[q] & 0x1FFFF) * SS;  // SS constexpr -> shift
            if constexpr (VW == 4)
                u[q] = *reinterpret_cast<const unsigned*>(xb + c);
            else
                u[q] = *reinterpret_cast<const unsigned short*>(xb + c);
        }
#pragma unroll
        for (int q = 0; q < 8; ++q) {
            float v = edge_val(w[q]);
            f32x2 lo = __builtin_amdgcn_cvt_pk_f32_fp8(u[q], false);
            acc[q & 3][0] += v * lo.x;
            acc[q & 3][1] += v * lo.y;
            if constexpr (VW == 4) {
                f32x2 hi = __builtin_amdgcn_cvt_pk_f32_fp8(u[q], true);
                acc[q & 3][2] += v * hi.x;
                acc[q & 3][3] += v * hi.y;
            }
        }
    }
    for (; j < end; ++j) {
        unsigned w = edges[j];
        float v = edge_val(w);
        size_t c = (size_t)(w & 0x1FFFF) * SS;
        unsigned u;
        if constexpr (VW == 4)
            u = *reinterpret_cast<const unsigned*>(xb + c);
        else
            u = *reinterpret_cast<const unsigned short*>(xb + c);
        f32x2 lo = __builtin_amdgcn_cvt_pk_f32_fp8(u, false);
        acc[0][0] += v * lo.x;
        acc[0][1] += v * lo.y;
        if constexpr (VW == 4) {
            f32x2 hi = __builtin_amdgcn_cvt_pk_f32_fp8(u, true);
            acc[0][2] += v * hi.x;
            acc[0][3] += v * hi.y;
        }
    }
    fvec res = (acc[0] + acc[1]) + (acc[2] + acc[3]);
    if constexpr (VW == 2) {
        unsigned o = (unsigned)f2bf(res[0]) | ((unsigned)f2bf(res[1]) << 16);
        __builtin_nontemporal_store(o,
            reinterpret_cast<unsigned*>(out + (size_t)r * OS + lane * 2));
    } else {
        u16x4 o;
#pragma unroll
        for (int q = 0; q < 4; ++q) o[q] = f2bf(res[q]);
        __builtin_nontemporal_store(o,
            reinterpret_cast<u16x4*>(out + (size_t)r * OS + lane * 4));
    }
}

// SpMM over fp8 y [nodes][64] + bias + log_softmax over first 40 lanes; NT final store
__global__ void spmm3_lsm_kernel(const int* __restrict__ offsets, const unsigned* __restrict__ edges,
                                 const unsigned char* __restrict__ y, const float* __restrict__ b3,
                                 float* __restrict__ out, int nRows) {
    int wave = threadIdx.x >> 6;
    int lane = threadIdx.x & 63;
    int r = blockIdx.x * 4 + wave;
    if (r >= nRows) return;
    int start = offsets[r], end = offsets[r + 1];
    float a0 = 0.f, a1 = 0.f, a2 = 0.f, a3 = 0.f;
    const unsigned char* yb = y + lane;
    int j = start;
    for (; j + 7 < end; j += 8) {
        unsigned w[8];
#pragma unroll
        for (int q = 0; q < 8; ++q) w[q] = edges[j + q];
        unsigned u[8];
#pragma unroll
        for (int q = 0; q < 8; ++q) u[q] = yb[(size_t)(w[q] & 0x1FFFF) * 64];
#pragma unroll
        for (int q = 0; q < 8; ++q) {
            float yv = __builtin_amdgcn_cvt_f32_fp8(u[q], 0);
            float v = edge_val(w[q]);
            if ((q & 3) == 0) a0 += v * yv;
            else if ((q & 3) == 1) a1 += v * yv;
            else if ((q & 3) == 2) a2 += v * yv;
            else a3 += v * yv;
        }
    }
    for (; j < end; ++j) {
        unsigned w = edges[j];
        float yv = __builtin_amdgcn_cvt_f32_fp8((unsigned)yb[(size_t)(w & 0x1FFFF) * 64], 0);
        a0 += edge_val(w) * yv;
    }
    float acc = (a0 + a1) + (a2 + a3);
    float val = (lane < 40) ? (acc + b3[lane]) : -INFINITY;
    float m = val;
    for (int s = 32; s >= 1; s >>= 1) m = fmaxf(m, __shfl_xor(m, s));
    float e = (lane < 40) ? expf(val - m) : 0.f;
    float sum = e;
    for (int s = 32; s >= 1; s >>= 1) sum += __shfl_xor(sum, s);
    if (lane < 40)
        __builtin_nontemporal_store(val - m - logf(sum), out + (size_t)r * 40 + lane);
}

// ================= MFMA GEMM (A bf16, W bf16; LDS-staged 128xBN tile) =================
// OUTM: 0 = fp32, 1 = bf16, 2 = fp8 e4m3 (clamped +-448).
template <int K, int BN, int WM, int WN, bool RELU, bool HASBIAS, int OUTM>
__global__ __launch_bounds__(256) void gemm_a16_kernel(const unsigned short* __restrict__ A,
                                                       const unsigned short* __restrict__ BhT,
                                                       const float* __restrict__ bias,
                                                       void* __restrict__ Cv, int Cstride,
                                                       int nodes) {
    constexpr int BM = 128;
    constexpr int KS = 40;
    constexpr int NFM = BM / WM / 16;
    constexpr int NFN = BN / WN / 16;
    constexpr int ASL = BM * 4 / 256;  // = 2
    constexpr int BSL = BN * 4 / 256;  // 2 (BN=128) or 1 (BN=64)
    __shared__ unsigned short As[BM * KS];
    __shared__ unsigned short Bs[BN * KS];
    int t = threadIdx.x;
    int w = t >> 6, lane = t & 63;
    int wm = w % WM, wn = w / WM;
    int m0 = blockIdx.x * BM;
    int n0 = blockIdx.y * BN;
    int fr = lane & 15, fg = lane >> 4;
    f32x4 acc[NFM][NFN];
#pragma unroll
    for (int i = 0; i < NFM; ++i)
#pragma unroll
        for (int j = 0; j < NFN; ++j) acc[i][j] = f32x4{0.f, 0.f, 0.f, 0.f};

    for (int k0 = 0; k0 < K; k0 += 32) {
        bf16x8 ar[ASL];
#pragma unroll
        for (int s = 0; s < ASL; ++s) {
            int slot = t + s * 256;
            int row = slot >> 2, kb = slot & 3;
            ar[s] = *reinterpret_cast<const bf16x8*>(&A[(size_t)(m0 + row) * K + k0 + kb * 8]);
        }
        bf16x8 bhr[BSL];
#pragma unroll
        for (int s = 0; s < BSL; ++s) {
            int slot = t + s * 256;
            int col = slot >> 2, kb = slot & 3;
            bhr[s] = *reinterpret_cast<const bf16x8*>(&BhT[(size_t)(n0 + col) * K + k0 + kb * 8]);
        }
        __syncthreads();  // prev-iter LDS reads done
#pragma unroll
        for (int s = 0; s < ASL; ++s) {
            int slot = t + s * 256;
            int row = slot >> 2, kb = slot & 3;
            *reinterpret_cast<bf16x8*>(&As[row * KS + kb * 8]) = ar[s];
        }
#pragma unroll
        for (int s = 0; s < BSL; ++s) {
            int slot = t + s * 256;
            int col = slot >> 2, kb = slot & 3;
            *reinterpret_cast<bf16x8*>(&Bs[col * KS + kb * 8]) = bhr[s];
        }
        __syncthreads();  // LDS ready
        bf16x8 af[NFM];
#pragma unroll
        for (int fm = 0; fm < NFM; ++fm) {
            int arow = wm * (BM / WM) + fm * 16 + fr;
            af[fm] = *reinterpret_cast<bf16x8*>(&As[arow * KS + fg * 8]);
        }
#pragma unroll
        for (int fn = 0; fn < NFN; ++fn) {
            int bc = wn * (BN / WN) + fn * 16 + fr;
            bf16x8 bh = *reinterpret_cast<bf16x8*>(&Bs[bc * KS + fg * 8]);
#pragma unroll
            for (int fm = 0; fm < NFM; ++fm) {
                acc[fm][fn] = __builtin_amdgcn_mfma_f32_16x16x32_bf16(af[fm], bh, acc[fm][fn], 0, 0, 0);
            }
        }
    }
    // epilogue: C/D mapping col = lane&15, row = (lane>>4)*4 + reg
#pragma unroll
    for (int fm = 0; fm < NFM; ++fm) {
#pragma unroll
        for (int fn = 0; fn < NFN; ++fn) {
            int col = n0 + wn * (BN / WN) + fn * 16 + fr;
            float bv = HASBIAS ? bias[col] : 0.f;
#pragma unroll
            for (int g = 0; g < 4; ++g) {
                int r = m0 + wm * (BM / WM) + fm * 16 + fg * 4 + g;
                if (r < nodes) {
                    float v = acc[fm][fn][g] + bv;
                    if (RELU) v = fmaxf(v, 0.f);
                    if (OUTM == 2) {
                        float c = fminf(fmaxf(v, -448.f), 448.f);
                        unsigned pk = __builtin_amdgcn_cvt_pk_fp8_f32(c, c, 0, false);
                        ((unsigned char*)Cv)[(size_t)r * Cstride + col] = (unsigned char)(pk & 0xFF);
                    } else if (OUTM == 1) {
                        ((unsigned short*)Cv)[(size_t)r * Cstride + col] = f2bf(v);
                    } else {
                        ((float*)Cv)[(size_t)r * Cstride + col] = v;
                    }
                }
            }
        }
    }
}

// ================= launch =================
extern "C" void kernel_launch(void* const* d_in, const int* in_sizes, int n_in,
                              void* d_out, int out_size, void* d_ws, size_t ws_size,
                              hipStream_t stream) {
    const float* x = (const float*)d_in[0];
    const int* erow = (const int*)d_in[1];
    const int* ecol = (const int*)d_in[2];
    const float* evals = (const float*)d_in[3];
    const float* W1 = (const float*)d_in[4];
    const float* b1 = (const float*)d_in[5];
    const float* W2 = (const float*)d_in[6];
    const float* b2 = (const float*)d_in[7];
    const float* W3 = (const float*)d_in[8];
    const float* b3 = (const float*)d_in[9];
    const float* gamma1 = (const float*)d_in[10];
    const float* beta1 = (const float*)d_in[11];
    const float* mean1 = (const float*)d_in[12];
    const float* var1 = (const float*)d_in[13];
    const float* gamma2 = (const float*)d_in[14];
    const float* beta2 = (const float*)d_in[15];
    const float* mean2 = (const float*)d_in[16];
    const float* var2 = (const float*)d_in[17];
    float* out = (float*)d_out;

    int nodes = in_sizes[0] / 128;
    int nE = in_sizes[1];
    int padRows = (nodes + 127) & ~127;  // 128-multiple for the GEMM tile
    int nB2 = (nodes + 127) >> 7;        // coarse buckets of 128 rows

    char* p = (char*)d_ws;
    auto carve = [&](size_t bytes) {
        void* r = (void*)p;
        p += (bytes + 255) & ~(size_t)255;
        return r;
    };
    int* offsets = (int*)carve((size_t)(nodes + 1) * 4);
    int* blockCounts = (int*)carve((size_t)B1 * nB2 * 4);
    int* bucketTotal = (int*)carve((size_t)nB2 * 4);
    int* bucketBase = (int*)carve((size_t)(nB2 + 1) * 4);
    unsigned* edges = (unsigned*)carve((size_t)nE * 4);
    unsigned short* WhT1 = (unsigned short*)carve(256 * 128 * 2);
    unsigned short* WhT2 = (unsigned short*)carve(256 * 256 * 2);
    unsigned short* WhT3 = (unsigned short*)carve(64 * 256 * 2);
    float* b1f = (float*)carve(256 * 4);
    float* b2f = (float*)carve(256 * 4);
    float* bufA = (float*)carve((size_t)padRows * 256 * 4);
    float* bufB = (float*)carve((size_t)padRows * 256 * 4);
    // aliases (sequential lifetimes):
    int2* tmp = (int2*)bufA;                        // CSR staging; dead before spmm1 writes h16
    unsigned char* xf8 = (unsigned char*)bufB;      // x fp8 [nodes][128]; dead after spmm1
    unsigned short* h16 = (unsigned short*)bufA;    // h bf16 [padRows][128]; dead after gemm1
    unsigned char* z1f8 = (unsigned char*)bufB;     // z1 fp8 [nodes][256]; dead after spmm2
    unsigned short* h2b16 = (unsigned short*)bufA;  // h2 bf16 [padRows][256]; dead after gemm2
    unsigned short* z2b16 = (unsigned short*)bufB;  // z2 bf16 [padRows][256]; dead after gemm3
    unsigned char* yf8 = (unsigned char*)bufA;      // y fp8 [padRows][64]; after h2 dies

    // ---- CSR build: count -> scan -> scatter -> per-bucket sort (no global atomics) ----
    int chunk = (nE + B1 - 1) / B1;
    count_kernel<<<B1, 256, 0, stream>>>(erow, blockCounts, nB2, nE, chunk);
    scan_buckets_kernel<<<nB2, 256, 0, stream>>>(blockCounts, bucketTotal, nB2);
    scan_total_kernel<<<1, 256, 0, stream>>>(bucketTotal, bucketBase, offsets, nB2, nodes);
    scatter2_kernel<<<B1, 256, 0, stream>>>(erow, ecol, evals, blockCounts, bucketBase, tmp, nB2,
                                            nE, chunk);
    bucket_sort2_kernel<<<nB2, 256, 0, stream>>>(bucketBase, tmp, edges, offsets, nodes);

    // ---- weight prep: fold BN into bf16 W, transpose ----
    fold_kernel<<<(128 * 256 + 255) / 256, 256, 0, stream>>>(W1, b1, gamma1, beta1, mean1, var1,
                                                             WhT1, b1f, 128, 256);
    fold_kernel<<<(256 * 256 + 255) / 256, 256, 0, stream>>>(W2, b2, gamma2, beta2, mean2, var2,
                                                             WhT2, b2f, 256, 256);
    w3_kernel<<<(64 * 256 + 255) / 256, 256, 0, stream>>>(W3, WhT3, 256);

    // ---- pipeline ----
    int gR = (nodes + 3) / 4;
    int gM = padRows / 128;

    // x -> fp8 (gather source for layer 1; N(0,1) values, e4m3-safe)
    int nX4 = nodes * 128 / 4;
    cvt_fp8_kernel<<<(nX4 + 255) / 256, 256, 0, stream>>>(x, (unsigned*)xf8, nX4);
    // layer 1: h(bf16) = A*x_fp8 ; z1(fp8) = relu(h @ W1' + b1')
    spmm_fp8_kernel<2, 128, 128><<<gR, 256, 0, stream>>>(offsets, edges, xf8, h16, nodes);
    gemm_a16_kernel<128, 128, 2, 2, true, true, 2><<<dim3(gM, 2), 256, 0, stream>>>(
        h16, WhT1, b1f, z1f8, 256, nodes);
    // layer 2: h2(bf16) = A*z1_fp8 (single 256-col pass); z2(bf16) = relu(h2 @ W2' + b2')
    spmm_fp8_kernel<4, 256, 256><<<gR, 256, 0, stream>>>(offsets, edges, z1f8, h2b16, nodes);
    gemm_a16_kernel<256, 128, 2, 2, true, true, 1><<<dim3(gM, 2), 256, 0, stream>>>(
        h2b16, WhT2, b2f, z2b16, 256, nodes);
    // layer 3 (reassociated): y(fp8) = z2 @ W3 (padded 64 cols); out = logsoftmax(A*y + b3)
    gemm_a16_kernel<256, 64, 4, 1, false, false, 2><<<dim3(gM, 1), 256, 0, stream>>>(
        z2b16, WhT3, nullptr, yf8, 64, nodes);
    spmm3_lsm_kernel<<<gR, 256, 0, stream>>>(offsets, edges, yf8, b3, out, nodes);
}